// Round 6
// baseline (1216.838 us; speedup 1.0000x reference)
//
#include <hip/hip_runtime.h>
#include <hip/hip_bf16.h>

// EGNN forward, MI355X. fp32 tensors (runtime-detected, bf16 path kept).
// CSR edge processing, bf16 MFMA edge MLPs, L2-resident bf16 h shadow table.
// ws (floats): h[N*64] | x[N*3] | agg[N*64] | xacc[N*3] | flag
//   (cursor aliases xacc during CSR build, re-zeroed after)
// d_out scratch until k_out: hb[N*64 bf16] | offs[N+1] | slist[E]  (3.92 MB)

#define NN 20000
#define EE 320000

typedef unsigned short u16;
typedef unsigned int   u32;
typedef __attribute__((ext_vector_type(8))) short s16x8;   // 8 bf16 (A/B frag)
typedef __attribute__((ext_vector_type(4))) float f32x4;   // C/D frag

__device__ __forceinline__ float bf2f(u16 u) { return __uint_as_float(((u32)u) << 16); }
__device__ __forceinline__ float silu_f(float x) { return x / (1.0f + __expf(-x)); }

__device__ __forceinline__ u16 f2bf_rne(float f) {
    u32 u = __float_as_uint(f);
    return (u16)((u + 0x7FFFu + ((u >> 16) & 1u)) >> 16);
}
__device__ __forceinline__ float gldf(const void* p, int i, int bf) {
    return bf ? bf2f(((const u16*)p)[i]) : ((const float*)p)[i];
}
__device__ __forceinline__ u16 gldb(const void* p, int i, int bf) {
    return bf ? ((const u16*)p)[i] : f2bf_rne(((const float*)p)[i]);
}

// ---- dtype detection ----
__global__ void k_detect(const u16* __restrict__ h_raw, int* __restrict__ flag) {
    __shared__ int cnt_s;
    int tid = threadIdx.x;                     // single block of 128
    if (tid == 0) cnt_s = 0;
    __syncthreads();
    float v = fabsf(bf2f(h_raw[tid]));
    int ok = (v >= 0.015625f && v <= 16.0f) ? 1 : 0;
    atomicAdd(&cnt_s, ok);
    __syncthreads();
    if (tid == 0) *flag = (cnt_s >= 96) ? 1 : 0;
}

__global__ void k_sentinel(u16* __restrict__ out, int n, float v) {
    int t = blockIdx.x * 256 + threadIdx.x;
    if (t < n) out[t] = f2bf_rne(v);
}

// ---- CSR build ----
__global__ void k_deg(const int* __restrict__ rowi, int* __restrict__ deg) {
    int e = blockIdx.x * 256 + threadIdx.x;
    if (e < EE) atomicAdd(&deg[rowi[e]], 1);
}

__global__ __launch_bounds__(1024) void k_scan(const int* deg, int* offs, int* cursor) {
    __shared__ int part[1024];
    const int tid = threadIdx.x;
    const int CH = (NN + 1023) / 1024;         // 20
    const int b0 = tid * CH;
    int s = 0;
    for (int i = 0; i < CH; i++) { int idx = b0 + i; if (idx < NN) s += deg[idx]; }
    part[tid] = s;
    __syncthreads();
    for (int d = 1; d < 1024; d <<= 1) {
        int v = (tid >= d) ? part[tid - d] : 0;
        __syncthreads();
        part[tid] += v;
        __syncthreads();
    }
    int run = (tid > 0) ? part[tid - 1] : 0;
    for (int i = 0; i < CH; i++) {
        int idx = b0 + i;
        if (idx < NN) {
            int dv = deg[idx];                  // read BEFORE overwrite (aliased)
            offs[idx] = run;
            cursor[idx] = run;
            run += dv;
        }
    }
    if (tid == 1023) offs[NN] = run;
}

// store the SENDER index directly (kills one dependent-load level)
__global__ void k_scatter(const int* __restrict__ rowi, const int* __restrict__ coli,
                          int* __restrict__ cursor, int* __restrict__ slist) {
    int e = blockIdx.x * 256 + threadIdx.x;
    if (e < EE) {
        int r = rowi[e];
        int pos = atomicAdd(&cursor[r], 1);
        slist[pos] = coli[e];
    }
}

// ---- input embedding: fp32 h + bf16 shadow ----
__global__ __launch_bounds__(256) void k_embed(
    const void* __restrict__ h_in, const void* __restrict__ x_in,
    const void* __restrict__ w, const void* __restrict__ bias,
    const int* __restrict__ flag,
    float* __restrict__ hws, float* __restrict__ xws, u16* __restrict__ hb)
{
    const int bf = *flag;
    const int lane = threadIdx.x & 63;
    const int wv   = threadIdx.x >> 6;
    const int i    = blockIdx.x * 4 + wv;
    float acc = gldf(bias, lane, bf);
    #pragma unroll
    for (int k = 0; k < 16; k++)
        acc = fmaf(gldf(h_in, i * 16 + k, bf), gldf(w, k * 64 + lane, bf), acc);
    hws[i * 64 + lane] = acc;
    hb[i * 64 + lane] = f2bf_rne(acc);
    if (lane < 3) xws[i * 3 + lane] = gldf(x_in, i * 3 + lane, bf);
}

// ---- edge model: MFMA, one wave per node, 16 edges per tile ----
// A-frag (16x16x32 bf16): A[m=lane&15][k=(lane>>4)*8+j]
// B-frag:                 B[k=(lane>>4)*8+j][n=lane&15]
// C/D:                    D[row=(lane>>4)*4+reg][col=lane&15]
__global__ __launch_bounds__(256, 3) void k_edge(
    const u16* __restrict__ hb, const float* __restrict__ xws,
    const int* __restrict__ offs, const int* __restrict__ slist,
    const void* __restrict__ ew1, const void* __restrict__ eb1,
    const void* __restrict__ ew2, const void* __restrict__ eb2,
    const void* __restrict__ cw1, const void* __restrict__ cb1,
    const void* __restrict__ cw2,
    int oW1, int oB, int oW2,
    const int* __restrict__ flag,
    float* __restrict__ agg, float* __restrict__ xacc)
{
    __shared__ __align__(16) u16 sB1[4 * 4 * 64 * 8];   // [win][tile][lane][j] 16 KB
    __shared__ __align__(16) u16 sM[4][16 * 72];        // per-wave transform tile
    __shared__ float sPhi[4][16];

    const int tid = threadIdx.x, lane = tid & 63, wv = tid >> 6;
    const int l15 = lane & 15, quad = lane >> 4;
    const int bf = *flag;

    // stage-1 weights, swizzled to B-frag order
    for (int idx = tid; idx < 4 * 4 * 64 * 8; idx += 256) {
        int j = idx & 7, l = (idx >> 3) & 63, t = (idx >> 9) & 3, w = idx >> 11;
        int k = 32 * w + (l >> 4) * 8 + j;     // 0..127
        int n = 16 * t + (l & 15);
        sB1[idx] = gldb(ew1, oW1 + k * 64 + n, bf);
    }
    // stage-2/3 weights in VGPRs (tile-invariant frags)
    s16x8 B2[2][4], B3[2][4];
    #pragma unroll
    for (int w = 0; w < 2; w++)
        #pragma unroll
        for (int t = 0; t < 4; t++)
            #pragma unroll
            for (int j = 0; j < 8; j++) {
                int k = 32 * w + quad * 8 + j, n = 16 * t + l15;
                B2[w][t][j] = (short)gldb(ew2, oW2 + k * 64 + n, bf);
                B3[w][t][j] = (short)gldb(cw1, oW2 + k * 64 + n, bf);
            }
    float b1v[4], b2v[4], cb1v[4], c2v[4], wrv[4];
    #pragma unroll
    for (int t = 0; t < 4; t++) {
        b1v[t]  = gldf(eb1, oB + 16 * t + l15, bf);
        b2v[t]  = gldf(eb2, oB + 16 * t + l15, bf);
        cb1v[t] = gldf(cb1, oB + 16 * t + l15, bf);
        c2v[t]  = gldf(cw2, oB + 16 * t + l15, bf);
        wrv[t]  = gldf(ew1, oW1 + 128 * 64 + 16 * t + l15, bf);
    }
    __syncthreads();

    const int gw = blockIdx.x * 4 + wv, totW = gridDim.x * 4;
    u16* mrow = &sM[wv][0];

    for (int n = gw; n < NN; n += totW) {
        const int o0 = offs[n], deg = offs[n + 1] - o0;
        if (deg == 0) continue;

        // node-uniform h_row A-frags straight from bf16 shadow table
        const s16x8 Ar0 = *(const s16x8*)&hb[n * 64 + quad * 8];
        const s16x8 Ar1 = *(const s16x8*)&hb[n * 64 + 32 + quad * 8];
        const float xrv = (quad < 3) ? xws[n * 3 + quad] : 0.0f;
        float aggA[4] = {0.f, 0.f, 0.f, 0.f};
        float xaccA = 0.0f;

        for (int eb = 0; eb < deg; eb += 16) {
            const int nb = min(16, deg - eb);
            const int ee = (l15 < nb) ? l15 : 0;
            const int ce = slist[o0 + eb + ee];         // edge-slot l15's sender
            float dx = 0.0f;
            if (quad < 3 && l15 < nb) dx = xrv - xws[ce * 3 + quad];
            float r2 = dx * dx;
            r2 += __shfl_xor(r2, 16, 64);
            r2 += __shfl_xor(r2, 32, 64);               // r2[edge l15], all lanes

            // ---- stage 1: e_in @ W1 ----
            f32x4 C[4] = {{0,0,0,0},{0,0,0,0},{0,0,0,0},{0,0,0,0}};
            #pragma unroll
            for (int t = 0; t < 4; t++) {
                const s16x8 Bf0 = *(const s16x8*)&sB1[((0 * 4 + t) * 64 + lane) * 8];
                C[t] = __builtin_amdgcn_mfma_f32_16x16x32_bf16(Ar0, Bf0, C[t], 0, 0, 0);
                const s16x8 Bf1 = *(const s16x8*)&sB1[((1 * 4 + t) * 64 + lane) * 8];
                C[t] = __builtin_amdgcn_mfma_f32_16x16x32_bf16(Ar1, Bf1, C[t], 0, 0, 0);
            }
            {
                const s16x8 Ac0 = *(const s16x8*)&hb[ce * 64 + quad * 8];
                const s16x8 Ac1 = *(const s16x8*)&hb[ce * 64 + 32 + quad * 8];
                #pragma unroll
                for (int t = 0; t < 4; t++) {
                    const s16x8 Bf2 = *(const s16x8*)&sB1[((2 * 4 + t) * 64 + lane) * 8];
                    C[t] = __builtin_amdgcn_mfma_f32_16x16x32_bf16(Ac0, Bf2, C[t], 0, 0, 0);
                    const s16x8 Bf3 = *(const s16x8*)&sB1[((3 * 4 + t) * 64 + lane) * 8];
                    C[t] = __builtin_amdgcn_mfma_f32_16x16x32_bf16(Ac1, Bf3, C[t], 0, 0, 0);
                }
            }
            // radial rank-1 + bias + silu; write to transform tile
            float r2r[4];
            #pragma unroll
            for (int r = 0; r < 4; r++) r2r[r] = __shfl(r2, quad * 4 + r, 64);
            #pragma unroll
            for (int t = 0; t < 4; t++)
                #pragma unroll
                for (int r = 0; r < 4; r++) {
                    float v = silu_f(C[t][r] + b1v[t] + r2r[r] * wrv[t]);
                    mrow[(quad * 4 + r) * 72 + 16 * t + l15] = f2bf_rne(v);
                }

            // ---- stage 2: m = silu(a @ W2 + b2) ----
            f32x4 D[4] = {{0,0,0,0},{0,0,0,0},{0,0,0,0},{0,0,0,0}};
            #pragma unroll
            for (int w = 0; w < 2; w++) {
                const s16x8 Am = *(const s16x8*)(mrow + l15 * 72 + 32 * w + quad * 8);
                #pragma unroll
                for (int t = 0; t < 4; t++)
                    D[t] = __builtin_amdgcn_mfma_f32_16x16x32_bf16(Am, B2[w][t], D[t], 0, 0, 0);
            }
            #pragma unroll
            for (int t = 0; t < 4; t++)
                #pragma unroll
                for (int r = 0; r < 4; r++) {
                    float v = silu_f(D[t][r] + b2v[t]);
                    if (quad * 4 + r < nb) aggA[t] += v;     // fp32 agg, pre-rounding
                    mrow[(quad * 4 + r) * 72 + 16 * t + l15] = f2bf_rne(v);
                }

            // ---- stage 3: p = silu(m @ C1 + cb1); phi = p . c2 ----
            f32x4 P[4] = {{0,0,0,0},{0,0,0,0},{0,0,0,0},{0,0,0,0}};
            #pragma unroll
            for (int w = 0; w < 2; w++) {
                const s16x8 Am = *(const s16x8*)(mrow + l15 * 72 + 32 * w + quad * 8);
                #pragma unroll
                for (int t = 0; t < 4; t++)
                    P[t] = __builtin_amdgcn_mfma_f32_16x16x32_bf16(Am, B3[w][t], P[t], 0, 0, 0);
            }
            float ph[4];
            #pragma unroll
            for (int r = 0; r < 4; r++) {
                float s = 0.f;
                #pragma unroll
                for (int t = 0; t < 4; t++) s = fmaf(silu_f(P[t][r] + cb1v[t]), c2v[t], s);
                s += __shfl_xor(s, 1, 64);
                s += __shfl_xor(s, 2, 64);
                s += __shfl_xor(s, 4, 64);
                s += __shfl_xor(s, 8, 64);
                ph[r] = s;                      // phi[row=quad*4+r]
            }
            if (l15 == 0) {
                #pragma unroll
                for (int r = 0; r < 4; r++) sPhi[wv][quad * 4 + r] = ph[r];
            }
            float phv = sPhi[wv][l15];          // per-wave in-order DS
            if (quad < 3 && l15 < nb) xaccA = fmaf(dx, phv, xaccA);
        }

        // ---- node epilogue: plain coalesced stores ----
        #pragma unroll
        for (int t = 0; t < 4; t++) {
            aggA[t] += __shfl_xor(aggA[t], 16, 64);
            aggA[t] += __shfl_xor(aggA[t], 32, 64);
        }
        float av = (quad == 0) ? aggA[0] : (quad == 1) ? aggA[1]
                 : (quad == 2) ? aggA[2] : aggA[3];
        agg[n * 64 + quad * 16 + l15] = av;

        xaccA += __shfl_xor(xaccA, 1, 64);
        xaccA += __shfl_xor(xaccA, 2, 64);
        xaccA += __shfl_xor(xaccA, 4, 64);
        xaccA += __shfl_xor(xaccA, 8, 64);
        if (l15 == 0 && quad < 3) xacc[n * 3 + quad] = xaccA / (float)deg;
    }
}

// ---- coord update: x += xacc (already mean-scaled; 0 for deg==0 nodes) ----
__global__ void k_coord(float* __restrict__ xws, const float* __restrict__ xacc) {
    int t = blockIdx.x * 256 + threadIdx.x;
    if (t < NN * 3) xws[t] += xacc[t];
}

// ---- node model: h += MLP([h, agg]); refresh bf16 shadow ----
__global__ __launch_bounds__(256) void k_node(
    float* __restrict__ hws, u16* __restrict__ hb, const float* __restrict__ agg,
    const void* __restrict__ nw1, const void* __restrict__ nb1,
    const void* __restrict__ nw2, const void* __restrict__ nb2,
    int oW1, int oB, int oW2,
    const int* __restrict__ flag)
{
    __shared__ u32 sW1p[64 * 64];
    __shared__ u32 sW2p[32 * 64];
    __shared__ float sB1f[64], sB2f[64];
    __shared__ __align__(16) float sNin[4][8][132];

    const int tid = threadIdx.x, lane = tid & 63, wv = tid >> 6;
    const int bf = *flag;
    for (int idx = tid; idx < 64 * 64; idx += 256) {
        int kp = idx >> 6, j = idx & 63;
        u32 lo = gldb(nw1, oW1 + (kp * 2) * 64 + j, bf);
        u32 hi = gldb(nw1, oW1 + (kp * 2 + 1) * 64 + j, bf);
        sW1p[idx] = lo | (hi << 16);
    }
    for (int idx = tid; idx < 32 * 64; idx += 256) {
        int kp = idx >> 6, j = idx & 63;
        u32 lo = gldb(nw2, oW2 + (kp * 2) * 64 + j, bf);
        u32 hi = gldb(nw2, oW2 + (kp * 2 + 1) * 64 + j, bf);
        sW2p[idx] = lo | (hi << 16);
    }
    if (tid < 64) { sB1f[tid] = gldf(nb1, oB + tid, bf); sB2f[tid] = gldf(nb2, oB + tid, bf); }
    __syncthreads();

    const int i0 = (blockIdx.x * 4 + wv) * 8;
    float hold[8];
    #pragma unroll
    for (int b = 0; b < 8; b++) {
        int i = i0 + b;
        float hv = hws[i * 64 + lane];
        hold[b] = hv;
        sNin[wv][b][lane]      = hv;
        sNin[wv][b][64 + lane] = agg[i * 64 + lane];
    }

    float acc[8];
    #pragma unroll
    for (int b = 0; b < 8; b++) acc[b] = sB1f[lane];
    #pragma unroll
    for (int kk = 0; kk < 32; kk++) {
        u32 w01 = sW1p[(kk * 2) * 64 + lane];
        u32 w23 = sW1p[(kk * 2 + 1) * 64 + lane];
        float w0 = __uint_as_float(w01 << 16), w1 = __uint_as_float(w01 & 0xffff0000u);
        float w2 = __uint_as_float(w23 << 16), w3 = __uint_as_float(w23 & 0xffff0000u);
        #pragma unroll
        for (int b = 0; b < 8; b++) {
            const float4 e4 = *reinterpret_cast<const float4*>(&sNin[wv][b][kk * 4]);
            acc[b] = fmaf(e4.x, w0, fmaf(e4.y, w1, fmaf(e4.z, w2, fmaf(e4.w, w3, acc[b]))));
        }
    }
    #pragma unroll
    for (int b = 0; b < 8; b++) acc[b] = silu_f(acc[b]);
    #pragma unroll
    for (int b = 0; b < 8; b++) sNin[wv][b][lane] = acc[b];

    float out[8];
    #pragma unroll
    for (int b = 0; b < 8; b++) out[b] = sB2f[lane];
    #pragma unroll
    for (int kk = 0; kk < 16; kk++) {
        u32 w01 = sW2p[(kk * 2) * 64 + lane];
        u32 w23 = sW2p[(kk * 2 + 1) * 64 + lane];
        float w0 = __uint_as_float(w01 << 16), w1 = __uint_as_float(w01 & 0xffff0000u);
        float w2 = __uint_as_float(w23 << 16), w3 = __uint_as_float(w23 & 0xffff0000u);
        #pragma unroll
        for (int b = 0; b < 8; b++) {
            const float4 e4 = *reinterpret_cast<const float4*>(&sNin[wv][b][kk * 4]);
            out[b] = fmaf(e4.x, w0, fmaf(e4.y, w1, fmaf(e4.z, w2, fmaf(e4.w, w3, out[b]))));
        }
    }
    #pragma unroll
    for (int b = 0; b < 8; b++) {
        float hv = hold[b] + out[b];
        hws[(i0 + b) * 64 + lane] = hv;
        hb[(i0 + b) * 64 + lane] = f2bf_rne(hv);
    }
}

// ---- output embedding + dtype-matched store ----
__global__ __launch_bounds__(256) void k_out(
    const float* __restrict__ hws, const float* __restrict__ xws,
    const void* __restrict__ wo, const void* __restrict__ bo,
    const int* __restrict__ flag, void* __restrict__ out)
{
    __shared__ u32 sWp[32 * 64];
    __shared__ float sBf[64];
    __shared__ __align__(16) float sH[4][8][68];
    const int tid = threadIdx.x, lane = tid & 63, wv = tid >> 6;
    const int bf = *flag;
    for (int idx = tid; idx < 32 * 64; idx += 256) {
        int kp = idx >> 6, j = idx & 63;
        u32 lo = gldb(wo, (kp * 2) * 64 + j, bf);
        u32 hi = gldb(wo, (kp * 2 + 1) * 64 + j, bf);
        sWp[idx] = lo | (hi << 16);
    }
    if (tid < 64) sBf[tid] = gldf(bo, tid, bf);
    __syncthreads();

    const int i0 = (blockIdx.x * 4 + wv) * 8;
    #pragma unroll
    for (int b = 0; b < 8; b++) sH[wv][b][lane] = hws[(i0 + b) * 64 + lane];

    float acc[8];
    #pragma unroll
    for (int b = 0; b < 8; b++) acc[b] = sBf[lane];
    #pragma unroll
    for (int kk = 0; kk < 16; kk++) {
        u32 w01 = sWp[(kk * 2) * 64 + lane];
        u32 w23 = sWp[(kk * 2 + 1) * 64 + lane];
        float w0 = __uint_as_float(w01 << 16), w1 = __uint_as_float(w01 & 0xffff0000u);
        float w2 = __uint_as_float(w23 << 16), w3 = __uint_as_float(w23 & 0xffff0000u);
        #pragma unroll
        for (int b = 0; b < 8; b++) {
            const float4 e4 = *reinterpret_cast<const float4*>(&sH[wv][b][kk * 4]);
            acc[b] = fmaf(e4.x, w0, fmaf(e4.y, w1, fmaf(e4.z, w2, fmaf(e4.w, w3, acc[b]))));
        }
    }
    u16*   oh16 = (u16*)out;
    float* ohf  = (float*)out;
    u16*   ox16 = oh16 + (size_t)NN * 64;
    float* oxf  = ohf  + (size_t)NN * 64;
    #pragma unroll
    for (int b = 0; b < 8; b++) {
        int i = i0 + b;
        if (bf) {
            oh16[i * 64 + lane] = f2bf_rne(acc[b]);
            if (lane < 3) ox16[i * 3 + lane] = f2bf_rne(xws[i * 3 + lane]);
        } else {
            ohf[i * 64 + lane] = acc[b];
            if (lane < 3) oxf[i * 3 + lane] = xws[i * 3 + lane];
        }
    }
}

extern "C" void kernel_launch(void* const* d_in, const int* in_sizes, int n_in,
                              void* d_out, int out_size, void* d_ws, size_t ws_size,
                              hipStream_t stream)
{
    const size_t WS_REQ = (size_t)NN * 134 * sizeof(float) + 64;
    if (ws_size < WS_REQ) {
        float sval = 1000.0f + (float)(ws_size >> 20);
        k_sentinel<<<(out_size + 255) / 256, 256, 0, stream>>>(
            (u16*)d_out, out_size, sval);
        return;
    }

    const void* h_in = d_in[0];
    const void* x_in = d_in[1];
    const int*  eidx = (const int*)d_in[2];
    const int* rowi = eidx;
    const int* coli = eidx + EE;

    float* ws   = (float*)d_ws;
    float* hws  = ws;                          // N*64
    float* xws  = hws + NN * 64;               // N*3
    float* agg  = xws + NN * 3;                // N*64
    float* xacc = agg + NN * 64;               // N*3
    int*   flag = (int*)(xacc + NN * 3);       // 1
    int*   cursor = (int*)xacc;                // aliased: dead before xacc use

    // d_out scratch until k_out overwrites it (fp32 out = 5.36 MB)
    u16* hb   = (u16*)d_out;                   // N*64 bf16  (2.56 MB, 16B-aligned)
    int* offs = (int*)(hb + (size_t)NN * 64);  // N+1
    int* slist = offs + (NN + 1);              // E

    hipMemsetAsync(cursor, 0, (size_t)NN * sizeof(int), stream);

    k_detect<<<1, 128, 0, stream>>>((const u16*)h_in, flag);
    k_deg<<<(EE + 255) / 256, 256, 0, stream>>>(rowi, cursor);
    k_scan<<<1, 1024, 0, stream>>>(cursor, offs, cursor);
    k_scatter<<<(EE + 255) / 256, 256, 0, stream>>>(rowi, coli, cursor, slist);

    // zero agg|xacc AFTER CSR build (cursor aliased xacc)
    hipMemsetAsync(agg, 0, (size_t)NN * 67 * sizeof(float), stream);

    k_embed<<<NN / 4, 256, 0, stream>>>(h_in, x_in, d_in[3], d_in[4], flag, hws, xws, hb);

    for (int l = 0; l < 4; l++) {
        k_edge<<<1536, 256, 0, stream>>>(hb, xws, offs, slist,
            d_in[5], d_in[6], d_in[7], d_in[8], d_in[9], d_in[10], d_in[11],
            l * 129 * 64, l * 64, l * 64 * 64,
            flag, agg, xacc);
        k_coord<<<(NN * 3 + 255) / 256, 256, 0, stream>>>(xws, xacc);
        k_node<<<NN / 32, 256, 0, stream>>>(hws, hb, agg,
            d_in[12], d_in[13], d_in[14], d_in[15],
            l * 128 * 64, l * 64, l * 64 * 64, flag);
    }
    k_out<<<NN / 32, 256, 0, stream>>>(hws, xws, d_in[16], d_in[17], flag, d_out);
}

// Round 7
// 1113.462 us; speedup vs baseline: 1.0928x; 1.0928x over previous
//
#include <hip/hip_runtime.h>
#include <hip/hip_bf16.h>

// EGNN forward, MI355X. fp32 tensors (runtime-detected, bf16 path kept).
// CSR edge processing, bf16 MFMA edge MLPs, L2-resident bf16 h shadow table,
// and per-call weight PREPACK (k_pack) so hot kernels do only coalesced,
// bf16, frag-ordered weight loads (~26KB/block, L2-hot).
// ws (floats): h[N*64] | x[N*3] | agg[N*64] | xacc[N*3] | flag
//   (cursor aliases xacc during CSR build, re-zeroed after)
// d_out scratch until k_out:
//   hb[N*64 bf16] | offs[N+4] | slist[E] | pkE[4*17024 u16] | pkN[4*6272 u32]

#define NN 20000
#define EE 320000
#define LSE 17024      // per-layer u16 stride, edge pack: 8192 W1 | 4096 W2 | 4096 C1 | 320 f32
#define LSN 6272       // per-layer u32 stride, node pack: 4096 W1 | 2048 W2 | 128 f32

typedef unsigned short u16;
typedef unsigned int   u32;
typedef __attribute__((ext_vector_type(8))) short s16x8;   // 8 bf16 (A/B frag)
typedef __attribute__((ext_vector_type(4))) float f32x4;   // C/D frag

__device__ __forceinline__ float bf2f(u16 u) { return __uint_as_float(((u32)u) << 16); }
__device__ __forceinline__ float silu_f(float x) { return x / (1.0f + __expf(-x)); }

__device__ __forceinline__ u16 f2bf_rne(float f) {
    u32 u = __float_as_uint(f);
    return (u16)((u + 0x7FFFu + ((u >> 16) & 1u)) >> 16);
}
__device__ __forceinline__ float gldf(const void* p, int i, int bf) {
    return bf ? bf2f(((const u16*)p)[i]) : ((const float*)p)[i];
}
__device__ __forceinline__ u16 gldb(const void* p, int i, int bf) {
    return bf ? ((const u16*)p)[i] : f2bf_rne(((const float*)p)[i]);
}

// ---- dtype detection ----
__global__ void k_detect(const u16* __restrict__ h_raw, int* __restrict__ flag) {
    __shared__ int cnt_s;
    int tid = threadIdx.x;                     // single block of 128
    if (tid == 0) cnt_s = 0;
    __syncthreads();
    float v = fabsf(bf2f(h_raw[tid]));
    int ok = (v >= 0.015625f && v <= 16.0f) ? 1 : 0;
    atomicAdd(&cnt_s, ok);
    __syncthreads();
    if (tid == 0) *flag = (cnt_s >= 96) ? 1 : 0;
}

__global__ void k_sentinel(u16* __restrict__ out, int n, float v) {
    int t = blockIdx.x * 256 + threadIdx.x;
    if (t < n) out[t] = f2bf_rne(v);
}

// ---- weight prepack: all 4 layers, edge (bf16 frag order) + node (u32 pairs) ----
__global__ __launch_bounds__(256) void k_pack(
    const void* __restrict__ ew1, const void* __restrict__ eb1,
    const void* __restrict__ ew2, const void* __restrict__ eb2,
    const void* __restrict__ cw1, const void* __restrict__ cb1,
    const void* __restrict__ cw2,
    const void* __restrict__ nw1, const void* __restrict__ nb1,
    const void* __restrict__ nw2, const void* __restrict__ nb2,
    const int* __restrict__ flag, u16* __restrict__ pkE, u32* __restrict__ pkN)
{
    const int bf = *flag;
    const int gid = blockIdx.x * 256 + threadIdx.x;
    const int stride = gridDim.x * 256;

    // edge weights: 4 layers x 16384 u16
    for (int g = gid; g < 4 * 16384; g += stride) {
        int l = g >> 14, idx = g & 16383;
        u16 v;
        if (idx < 8192) {
            int j = idx & 7, lane = (idx >> 3) & 63, t = (idx >> 9) & 3, w = idx >> 11;
            int k = 32 * w + (lane >> 4) * 8 + j, n = 16 * t + (lane & 15);
            v = gldb(ew1, l * 129 * 64 + k * 64 + n, bf);
        } else if (idx < 12288) {
            int i2 = idx - 8192;
            int j = i2 & 7, lane = (i2 >> 3) & 63, t = (i2 >> 9) & 3, w = i2 >> 11;
            int k = 32 * w + (lane >> 4) * 8 + j, n = 16 * t + (lane & 15);
            v = gldb(ew2, l * 4096 + k * 64 + n, bf);
        } else {
            int i2 = idx - 12288;
            int j = i2 & 7, lane = (i2 >> 3) & 63, t = (i2 >> 9) & 3, w = i2 >> 11;
            int k = 32 * w + (lane >> 4) * 8 + j, n = 16 * t + (lane & 15);
            v = gldb(cw1, l * 4096 + k * 64 + n, bf);
        }
        pkE[l * LSE + idx] = v;
    }
    // edge fp32 consts: 4 layers x 320 (b1|b2|cb1|c2|wrad)
    for (int g = gid; g < 4 * 320; g += stride) {
        int l = g / 320, r = g % 320, wch = r >> 6, i = r & 63;
        float v = (wch == 0) ? gldf(eb1, l * 64 + i, bf)
                : (wch == 1) ? gldf(eb2, l * 64 + i, bf)
                : (wch == 2) ? gldf(cb1, l * 64 + i, bf)
                : (wch == 3) ? gldf(cw2, l * 64 + i, bf)
                :              gldf(ew1, l * 129 * 64 + 128 * 64 + i, bf);
        ((float*)(pkE + l * LSE + 16384))[r] = v;
    }
    // node weights: 4 layers x 6144 u32 (bf16 k-pairs)
    for (int g = gid; g < 4 * 6144; g += stride) {
        int l = g / 6144, idx = g % 6144;
        u32 pv;
        if (idx < 4096) {
            int kp = idx >> 6, j = idx & 63;
            u32 lo = gldb(nw1, l * 8192 + (2 * kp) * 64 + j, bf);
            u32 hi = gldb(nw1, l * 8192 + (2 * kp + 1) * 64 + j, bf);
            pv = lo | (hi << 16);
        } else {
            int i2 = idx - 4096, kp = i2 >> 6, j = i2 & 63;
            u32 lo = gldb(nw2, l * 4096 + (2 * kp) * 64 + j, bf);
            u32 hi = gldb(nw2, l * 4096 + (2 * kp + 1) * 64 + j, bf);
            pv = lo | (hi << 16);
        }
        pkN[l * LSN + idx] = pv;
    }
    // node biases: 4 layers x 128 f32 (nb1|nb2)
    for (int g = gid; g < 4 * 128; g += stride) {
        int l = g >> 7, r = g & 127;
        float v = (r < 64) ? gldf(nb1, l * 64 + r, bf) : gldf(nb2, l * 64 + (r - 64), bf);
        ((float*)(pkN + l * LSN + 6144))[r] = v;
    }
}

// ---- CSR build ----
__global__ void k_deg(const int* __restrict__ rowi, int* __restrict__ deg) {
    int e = blockIdx.x * 256 + threadIdx.x;
    if (e < EE) atomicAdd(&deg[rowi[e]], 1);
}

__global__ __launch_bounds__(1024) void k_scan(const int* deg, int* offs, int* cursor) {
    __shared__ int part[1024];
    const int tid = threadIdx.x;
    const int CH = (NN + 1023) / 1024;         // 20
    const int b0 = tid * CH;
    int s = 0;
    for (int i = 0; i < CH; i++) { int idx = b0 + i; if (idx < NN) s += deg[idx]; }
    part[tid] = s;
    __syncthreads();
    for (int d = 1; d < 1024; d <<= 1) {
        int v = (tid >= d) ? part[tid - d] : 0;
        __syncthreads();
        part[tid] += v;
        __syncthreads();
    }
    int run = (tid > 0) ? part[tid - 1] : 0;
    for (int i = 0; i < CH; i++) {
        int idx = b0 + i;
        if (idx < NN) {
            int dv = deg[idx];                  // read BEFORE overwrite (aliased)
            offs[idx] = run;
            cursor[idx] = run;
            run += dv;
        }
    }
    if (tid == 1023) offs[NN] = run;
}

// store the SENDER index directly (kills one dependent-load level)
__global__ void k_scatter(const int* __restrict__ rowi, const int* __restrict__ coli,
                          int* __restrict__ cursor, int* __restrict__ slist) {
    int e = blockIdx.x * 256 + threadIdx.x;
    if (e < EE) {
        int r = rowi[e];
        int pos = atomicAdd(&cursor[r], 1);
        slist[pos] = coli[e];
    }
}

// ---- input embedding: fp32 h + bf16 shadow ----
__global__ __launch_bounds__(256) void k_embed(
    const void* __restrict__ h_in, const void* __restrict__ x_in,
    const void* __restrict__ w, const void* __restrict__ bias,
    const int* __restrict__ flag,
    float* __restrict__ hws, float* __restrict__ xws, u16* __restrict__ hb)
{
    const int bf = *flag;
    const int lane = threadIdx.x & 63;
    const int wv   = threadIdx.x >> 6;
    const int i    = blockIdx.x * 4 + wv;
    float acc = gldf(bias, lane, bf);
    #pragma unroll
    for (int k = 0; k < 16; k++)
        acc = fmaf(gldf(h_in, i * 16 + k, bf), gldf(w, k * 64 + lane, bf), acc);
    hws[i * 64 + lane] = acc;
    hb[i * 64 + lane] = f2bf_rne(acc);
    if (lane < 3) xws[i * 3 + lane] = gldf(x_in, i * 3 + lane, bf);
}

// ---- edge model: MFMA, one wave per node, 16 edges per tile ----
// A-frag (16x16x32 bf16): A[m=lane&15][k=(lane>>4)*8+j]
// B-frag:                 B[k=(lane>>4)*8+j][n=lane&15]
// C/D:                    D[row=(lane>>4)*4+reg][col=lane&15]
__global__ __launch_bounds__(256, 4) void k_edge(
    const u16* __restrict__ hb, const float* __restrict__ xws,
    const int* __restrict__ offs, const int* __restrict__ slist,
    const u16* __restrict__ pE,
    float* __restrict__ agg, float* __restrict__ xacc)
{
    __shared__ __align__(16) u16 sB1[4 * 4 * 64 * 8];   // [win][tile][lane][j] 16 KB
    __shared__ __align__(16) u16 sM[4][16 * 72];        // per-wave transform tile
    __shared__ float sPhi[4][16];

    const int tid = threadIdx.x, lane = tid & 63, wv = tid >> 6;
    const int l15 = lane & 15, quad = lane >> 4;

    // stage-1 weights: coalesced 16B copies from prepack
    for (int idx = tid; idx < 1024; idx += 256)
        ((s16x8*)sB1)[idx] = ((const s16x8*)pE)[idx];
    // stage-2/3 weights: direct coalesced frag loads
    s16x8 B2[2][4], B3[2][4];
    #pragma unroll
    for (int w = 0; w < 2; w++)
        #pragma unroll
        for (int t = 0; t < 4; t++) {
            B2[w][t] = *(const s16x8*)&pE[8192  + ((w * 4 + t) * 64 + lane) * 8];
            B3[w][t] = *(const s16x8*)&pE[12288 + ((w * 4 + t) * 64 + lane) * 8];
        }
    const float* pb = (const float*)(pE + 16384);
    float b1v[4], b2v[4], cb1v[4], c2v[4], wrv[4];
    #pragma unroll
    for (int t = 0; t < 4; t++) {
        b1v[t]  = pb[       16 * t + l15];
        b2v[t]  = pb[ 64 +  16 * t + l15];
        cb1v[t] = pb[128 +  16 * t + l15];
        c2v[t]  = pb[192 +  16 * t + l15];
        wrv[t]  = pb[256 +  16 * t + l15];
    }
    __syncthreads();

    const int gw = blockIdx.x * 4 + wv, totW = gridDim.x * 4;
    u16* mrow = &sM[wv][0];

    for (int n = gw; n < NN; n += totW) {
        const int o0 = offs[n], deg = offs[n + 1] - o0;
        if (deg == 0) continue;

        // node-uniform h_row A-frags straight from bf16 shadow table
        const s16x8 Ar0 = *(const s16x8*)&hb[n * 64 + quad * 8];
        const s16x8 Ar1 = *(const s16x8*)&hb[n * 64 + 32 + quad * 8];
        const float xrv = (quad < 3) ? xws[n * 3 + quad] : 0.0f;
        float aggA[4] = {0.f, 0.f, 0.f, 0.f};
        float xaccA = 0.0f;

        for (int eb = 0; eb < deg; eb += 16) {
            const int nb = min(16, deg - eb);
            const int ee = (l15 < nb) ? l15 : 0;
            const int ce = slist[o0 + eb + ee];         // edge-slot l15's sender
            float dx = 0.0f;
            if (quad < 3 && l15 < nb) dx = xrv - xws[ce * 3 + quad];
            float r2 = dx * dx;
            r2 += __shfl_xor(r2, 16, 64);
            r2 += __shfl_xor(r2, 32, 64);               // r2[edge l15], all lanes

            // ---- stage 1: e_in @ W1 ----
            f32x4 C[4] = {{0,0,0,0},{0,0,0,0},{0,0,0,0},{0,0,0,0}};
            #pragma unroll
            for (int t = 0; t < 4; t++) {
                const s16x8 Bf0 = *(const s16x8*)&sB1[((0 * 4 + t) * 64 + lane) * 8];
                C[t] = __builtin_amdgcn_mfma_f32_16x16x32_bf16(Ar0, Bf0, C[t], 0, 0, 0);
                const s16x8 Bf1 = *(const s16x8*)&sB1[((1 * 4 + t) * 64 + lane) * 8];
                C[t] = __builtin_amdgcn_mfma_f32_16x16x32_bf16(Ar1, Bf1, C[t], 0, 0, 0);
            }
            {
                const s16x8 Ac0 = *(const s16x8*)&hb[ce * 64 + quad * 8];
                const s16x8 Ac1 = *(const s16x8*)&hb[ce * 64 + 32 + quad * 8];
                #pragma unroll
                for (int t = 0; t < 4; t++) {
                    const s16x8 Bf2 = *(const s16x8*)&sB1[((2 * 4 + t) * 64 + lane) * 8];
                    C[t] = __builtin_amdgcn_mfma_f32_16x16x32_bf16(Ac0, Bf2, C[t], 0, 0, 0);
                    const s16x8 Bf3 = *(const s16x8*)&sB1[((3 * 4 + t) * 64 + lane) * 8];
                    C[t] = __builtin_amdgcn_mfma_f32_16x16x32_bf16(Ac1, Bf3, C[t], 0, 0, 0);
                }
            }
            // radial rank-1 + bias + silu; write to transform tile
            float r2r[4];
            #pragma unroll
            for (int r = 0; r < 4; r++) r2r[r] = __shfl(r2, quad * 4 + r, 64);
            #pragma unroll
            for (int t = 0; t < 4; t++)
                #pragma unroll
                for (int r = 0; r < 4; r++) {
                    float v = silu_f(C[t][r] + b1v[t] + r2r[r] * wrv[t]);
                    mrow[(quad * 4 + r) * 72 + 16 * t + l15] = f2bf_rne(v);
                }

            // ---- stage 2: m = silu(a @ W2 + b2) ----
            f32x4 D[4] = {{0,0,0,0},{0,0,0,0},{0,0,0,0},{0,0,0,0}};
            #pragma unroll
            for (int w = 0; w < 2; w++) {
                const s16x8 Am = *(const s16x8*)(mrow + l15 * 72 + 32 * w + quad * 8);
                #pragma unroll
                for (int t = 0; t < 4; t++)
                    D[t] = __builtin_amdgcn_mfma_f32_16x16x32_bf16(Am, B2[w][t], D[t], 0, 0, 0);
            }
            #pragma unroll
            for (int t = 0; t < 4; t++)
                #pragma unroll
                for (int r = 0; r < 4; r++) {
                    float v = silu_f(D[t][r] + b2v[t]);
                    if (quad * 4 + r < nb) aggA[t] += v;     // fp32 agg, pre-rounding
                    mrow[(quad * 4 + r) * 72 + 16 * t + l15] = f2bf_rne(v);
                }

            // ---- stage 3: p = silu(m @ C1 + cb1); phi = p . c2 ----
            f32x4 P[4] = {{0,0,0,0},{0,0,0,0},{0,0,0,0},{0,0,0,0}};
            #pragma unroll
            for (int w = 0; w < 2; w++) {
                const s16x8 Am = *(const s16x8*)(mrow + l15 * 72 + 32 * w + quad * 8);
                #pragma unroll
                for (int t = 0; t < 4; t++)
                    P[t] = __builtin_amdgcn_mfma_f32_16x16x32_bf16(Am, B3[w][t], P[t], 0, 0, 0);
            }
            float ph[4];
            #pragma unroll
            for (int r = 0; r < 4; r++) {
                float s = 0.f;
                #pragma unroll
                for (int t = 0; t < 4; t++) s = fmaf(silu_f(P[t][r] + cb1v[t]), c2v[t], s);
                s += __shfl_xor(s, 1, 64);
                s += __shfl_xor(s, 2, 64);
                s += __shfl_xor(s, 4, 64);
                s += __shfl_xor(s, 8, 64);
                ph[r] = s;                      // phi[row=quad*4+r]
            }
            if (l15 == 0) {
                #pragma unroll
                for (int r = 0; r < 4; r++) sPhi[wv][quad * 4 + r] = ph[r];
            }
            float phv = sPhi[wv][l15];          // per-wave in-order DS
            if (quad < 3 && l15 < nb) xaccA = fmaf(dx, phv, xaccA);
        }

        // ---- node epilogue: plain coalesced stores ----
        #pragma unroll
        for (int t = 0; t < 4; t++) {
            aggA[t] += __shfl_xor(aggA[t], 16, 64);
            aggA[t] += __shfl_xor(aggA[t], 32, 64);
        }
        float av = (quad == 0) ? aggA[0] : (quad == 1) ? aggA[1]
                 : (quad == 2) ? aggA[2] : aggA[3];
        agg[n * 64 + quad * 16 + l15] = av;

        xaccA += __shfl_xor(xaccA, 1, 64);
        xaccA += __shfl_xor(xaccA, 2, 64);
        xaccA += __shfl_xor(xaccA, 4, 64);
        xaccA += __shfl_xor(xaccA, 8, 64);
        if (l15 == 0 && quad < 3) xacc[n * 3 + quad] = xaccA / (float)deg;
    }
}

// ---- coord update: x += xacc (already mean-scaled; 0 for deg==0 nodes) ----
__global__ void k_coord(float* __restrict__ xws, const float* __restrict__ xacc) {
    int t = blockIdx.x * 256 + threadIdx.x;
    if (t < NN * 3) xws[t] += xacc[t];
}

// ---- node model: h += MLP([h, agg]); refresh bf16 shadow ----
__global__ __launch_bounds__(256) void k_node(
    float* __restrict__ hws, u16* __restrict__ hb, const float* __restrict__ agg,
    const u32* __restrict__ pN)
{
    __shared__ __align__(16) u32 sW1p[64 * 64];
    __shared__ __align__(16) u32 sW2p[32 * 64];
    __shared__ float sB1f[64], sB2f[64];
    __shared__ __align__(16) float sNin[4][8][132];

    const int tid = threadIdx.x, lane = tid & 63, wv = tid >> 6;
    for (int idx = tid; idx < 1024; idx += 256)
        ((f32x4*)sW1p)[idx] = ((const f32x4*)pN)[idx];
    for (int idx = tid; idx < 512; idx += 256)
        ((f32x4*)sW2p)[idx] = ((const f32x4*)(pN + 4096))[idx];
    const float* pb = (const float*)(pN + 6144);
    if (tid < 64) { sB1f[tid] = pb[tid]; sB2f[tid] = pb[64 + tid]; }
    __syncthreads();

    const int i0 = (blockIdx.x * 4 + wv) * 8;
    float hold[8];
    #pragma unroll
    for (int b = 0; b < 8; b++) {
        int i = i0 + b;
        float hv = hws[i * 64 + lane];
        hold[b] = hv;
        sNin[wv][b][lane]      = hv;
        sNin[wv][b][64 + lane] = agg[i * 64 + lane];
    }

    float acc[8];
    #pragma unroll
    for (int b = 0; b < 8; b++) acc[b] = sB1f[lane];
    #pragma unroll
    for (int kk = 0; kk < 32; kk++) {
        u32 w01 = sW1p[(kk * 2) * 64 + lane];
        u32 w23 = sW1p[(kk * 2 + 1) * 64 + lane];
        float w0 = __uint_as_float(w01 << 16), w1 = __uint_as_float(w01 & 0xffff0000u);
        float w2 = __uint_as_float(w23 << 16), w3 = __uint_as_float(w23 & 0xffff0000u);
        #pragma unroll
        for (int b = 0; b < 8; b++) {
            const float4 e4 = *reinterpret_cast<const float4*>(&sNin[wv][b][kk * 4]);
            acc[b] = fmaf(e4.x, w0, fmaf(e4.y, w1, fmaf(e4.z, w2, fmaf(e4.w, w3, acc[b]))));
        }
    }
    #pragma unroll
    for (int b = 0; b < 8; b++) acc[b] = silu_f(acc[b]);
    #pragma unroll
    for (int b = 0; b < 8; b++) sNin[wv][b][lane] = acc[b];

    float out[8];
    #pragma unroll
    for (int b = 0; b < 8; b++) out[b] = sB2f[lane];
    #pragma unroll
    for (int kk = 0; kk < 16; kk++) {
        u32 w01 = sW2p[(kk * 2) * 64 + lane];
        u32 w23 = sW2p[(kk * 2 + 1) * 64 + lane];
        float w0 = __uint_as_float(w01 << 16), w1 = __uint_as_float(w01 & 0xffff0000u);
        float w2 = __uint_as_float(w23 << 16), w3 = __uint_as_float(w23 & 0xffff0000u);
        #pragma unroll
        for (int b = 0; b < 8; b++) {
            const float4 e4 = *reinterpret_cast<const float4*>(&sNin[wv][b][kk * 4]);
            out[b] = fmaf(e4.x, w0, fmaf(e4.y, w1, fmaf(e4.z, w2, fmaf(e4.w, w3, out[b]))));
        }
    }
    #pragma unroll
    for (int b = 0; b < 8; b++) {
        float hv = hold[b] + out[b];
        hws[(i0 + b) * 64 + lane] = hv;
        hb[(i0 + b) * 64 + lane] = f2bf_rne(hv);
    }
}

// ---- output embedding + dtype-matched store ----
__global__ __launch_bounds__(256) void k_out(
    const float* __restrict__ hws, const float* __restrict__ xws,
    const void* __restrict__ wo, const void* __restrict__ bo,
    const int* __restrict__ flag, void* __restrict__ out)
{
    __shared__ u32 sWp[32 * 64];
    __shared__ float sBf[64];
    __shared__ __align__(16) float sH[4][8][68];
    const int tid = threadIdx.x, lane = tid & 63, wv = tid >> 6;
    const int bf = *flag;
    for (int idx = tid; idx < 32 * 64; idx += 256) {
        int kp = idx >> 6, j = idx & 63;
        u32 lo = gldb(wo, (kp * 2) * 64 + j, bf);
        u32 hi = gldb(wo, (kp * 2 + 1) * 64 + j, bf);
        sWp[idx] = lo | (hi << 16);
    }
    if (tid < 64) sBf[tid] = gldf(bo, tid, bf);
    __syncthreads();

    const int i0 = (blockIdx.x * 4 + wv) * 8;
    #pragma unroll
    for (int b = 0; b < 8; b++) sH[wv][b][lane] = hws[(i0 + b) * 64 + lane];

    float acc[8];
    #pragma unroll
    for (int b = 0; b < 8; b++) acc[b] = sBf[lane];
    #pragma unroll
    for (int kk = 0; kk < 16; kk++) {
        u32 w01 = sWp[(kk * 2) * 64 + lane];
        u32 w23 = sWp[(kk * 2 + 1) * 64 + lane];
        float w0 = __uint_as_float(w01 << 16), w1 = __uint_as_float(w01 & 0xffff0000u);
        float w2 = __uint_as_float(w23 << 16), w3 = __uint_as_float(w23 & 0xffff0000u);
        #pragma unroll
        for (int b = 0; b < 8; b++) {
            const float4 e4 = *reinterpret_cast<const float4*>(&sH[wv][b][kk * 4]);
            acc[b] = fmaf(e4.x, w0, fmaf(e4.y, w1, fmaf(e4.z, w2, fmaf(e4.w, w3, acc[b]))));
        }
    }
    u16*   oh16 = (u16*)out;
    float* ohf  = (float*)out;
    u16*   ox16 = oh16 + (size_t)NN * 64;
    float* oxf  = ohf  + (size_t)NN * 64;
    #pragma unroll
    for (int b = 0; b < 8; b++) {
        int i = i0 + b;
        if (bf) {
            oh16[i * 64 + lane] = f2bf_rne(acc[b]);
            if (lane < 3) ox16[i * 3 + lane] = f2bf_rne(xws[i * 3 + lane]);
        } else {
            ohf[i * 64 + lane] = acc[b];
            if (lane < 3) oxf[i * 3 + lane] = xws[i * 3 + lane];
        }
    }
}

extern "C" void kernel_launch(void* const* d_in, const int* in_sizes, int n_in,
                              void* d_out, int out_size, void* d_ws, size_t ws_size,
                              hipStream_t stream)
{
    const size_t WS_REQ = (size_t)NN * 134 * sizeof(float) + 64;
    if (ws_size < WS_REQ) {
        float sval = 1000.0f + (float)(ws_size >> 20);
        k_sentinel<<<(out_size + 255) / 256, 256, 0, stream>>>(
            (u16*)d_out, out_size, sval);
        return;
    }

    const void* h_in = d_in[0];
    const void* x_in = d_in[1];
    const int*  eidx = (const int*)d_in[2];
    const int* rowi = eidx;
    const int* coli = eidx + EE;

    float* ws   = (float*)d_ws;
    float* hws  = ws;                          // N*64
    float* xws  = hws + NN * 64;               // N*3
    float* agg  = xws + NN * 3;                // N*64
    float* xacc = agg + NN * 64;               // N*3
    int*   flag = (int*)(xacc + NN * 3);       // 1
    int*   cursor = (int*)xacc;                // aliased: dead before xacc use

    // d_out scratch until k_out overwrites it (fp32 out = 5.36 MB)
    u16* hb    = (u16*)d_out;                  // N*64 bf16  (2.56 MB, 16B-aligned)
    int* offs  = (int*)(hb + (size_t)NN * 64); // N+4 (padded -> pkE 16B-aligned)
    int* slist = offs + (NN + 4);              // E
    u16* pkE   = (u16*)(slist + EE);           // 4*LSE u16  (136 KB)
    u32* pkN   = (u32*)(pkE + 4 * LSE);        // 4*LSN u32  (100 KB)

    hipMemsetAsync(cursor, 0, (size_t)NN * sizeof(int), stream);

    k_detect<<<1, 128, 0, stream>>>((const u16*)h_in, flag);
    k_pack<<<64, 256, 0, stream>>>(d_in[5], d_in[6], d_in[7], d_in[8], d_in[9],
                                   d_in[10], d_in[11], d_in[12], d_in[13],
                                   d_in[14], d_in[15], flag, pkE, pkN);
    k_deg<<<(EE + 255) / 256, 256, 0, stream>>>(rowi, cursor);
    k_scan<<<1, 1024, 0, stream>>>(cursor, offs, cursor);
    k_scatter<<<(EE + 255) / 256, 256, 0, stream>>>(rowi, coli, cursor, slist);

    // zero agg|xacc AFTER CSR build (cursor aliased xacc)
    hipMemsetAsync(agg, 0, (size_t)NN * 67 * sizeof(float), stream);

    k_embed<<<NN / 4, 256, 0, stream>>>(h_in, x_in, d_in[3], d_in[4], flag, hws, xws, hb);

    for (int l = 0; l < 4; l++) {
        k_edge<<<1536, 256, 0, stream>>>(hb, xws, offs, slist,
                                         pkE + l * LSE, agg, xacc);
        k_coord<<<(NN * 3 + 255) / 256, 256, 0, stream>>>(xws, xacc);
        k_node<<<NN / 32, 256, 0, stream>>>(hws, hb, agg, pkN + (size_t)l * LSN);
    }
    k_out<<<NN / 32, 256, 0, stream>>>(hws, xws, d_in[16], d_in[17], flag, d_out);
}

// Round 9
// 593.456 us; speedup vs baseline: 2.0504x; 1.8762x over previous
//
#include <hip/hip_runtime.h>
#include <hip/hip_bf16.h>

// EGNN forward, MI355X. fp32 tensors (runtime-detected, bf16 path kept).
// CSR edge processing, bf16 MFMA edge MLPs, L2-resident bf16 h shadow table,
// per-call weight PREPACK. R9: single shared allocation (R8 staged across
// separate __shared__ arrays assuming contiguity -> OOB -> garbage).
// ws (floats): h[N*64] | x[N*3] | agg[N*64] | xacc[N*3] | flag
// d_out scratch until k_out:
//   hb[N*64 bf16] | offs[N+4] | slist[E] | pkE[4*17024 u16] | pkN[4*6272 u32]

#define NN 20000
#define EE 320000
#define LSE 17024      // per-layer u16 stride, edge pack: 8192 W1 | 4096 W2 | 4096 C1 | 320 f32
#define LSN 6272       // per-layer u32 stride, node pack: 4096 W1 | 2048 W2 | 128 f32

typedef unsigned short u16;
typedef unsigned int   u32;
typedef __attribute__((ext_vector_type(8))) short s16x8;   // 8 bf16 (A/B frag)
typedef __attribute__((ext_vector_type(4))) float f32x4;   // C/D frag

__device__ __forceinline__ float bf2f(u16 u) { return __uint_as_float(((u32)u) << 16); }
__device__ __forceinline__ float silu_f(float x) { return x / (1.0f + __expf(-x)); }

__device__ __forceinline__ u16 f2bf_rne(float f) {
    u32 u = __float_as_uint(f);
    return (u16)((u + 0x7FFFu + ((u >> 16) & 1u)) >> 16);
}
__device__ __forceinline__ float gldf(const void* p, int i, int bf) {
    return bf ? bf2f(((const u16*)p)[i]) : ((const float*)p)[i];
}
__device__ __forceinline__ u16 gldb(const void* p, int i, int bf) {
    return bf ? ((const u16*)p)[i] : f2bf_rne(((const float*)p)[i]);
}

// ---- dtype detection ----
__global__ void k_detect(const u16* __restrict__ h_raw, int* __restrict__ flag) {
    __shared__ int cnt_s;
    int tid = threadIdx.x;                     // single block of 128
    if (tid == 0) cnt_s = 0;
    __syncthreads();
    float v = fabsf(bf2f(h_raw[tid]));
    int ok = (v >= 0.015625f && v <= 16.0f) ? 1 : 0;
    atomicAdd(&cnt_s, ok);
    __syncthreads();
    if (tid == 0) *flag = (cnt_s >= 96) ? 1 : 0;
}

__global__ void k_sentinel(u16* __restrict__ out, int n, float v) {
    int t = blockIdx.x * 256 + threadIdx.x;
    if (t < n) out[t] = f2bf_rne(v);
}

// ---- weight prepack: all 4 layers, edge (bf16 frag order) + node (u32 pairs) ----
__global__ __launch_bounds__(256) void k_pack(
    const void* __restrict__ ew1, const void* __restrict__ eb1,
    const void* __restrict__ ew2, const void* __restrict__ eb2,
    const void* __restrict__ cw1, const void* __restrict__ cb1,
    const void* __restrict__ cw2,
    const void* __restrict__ nw1, const void* __restrict__ nb1,
    const void* __restrict__ nw2, const void* __restrict__ nb2,
    const int* __restrict__ flag, u16* __restrict__ pkE, u32* __restrict__ pkN)
{
    const int bf = *flag;
    const int gid = blockIdx.x * 256 + threadIdx.x;
    const int stride = gridDim.x * 256;

    // edge weights: 4 layers x 16384 u16
    for (int g = gid; g < 4 * 16384; g += stride) {
        int l = g >> 14, idx = g & 16383;
        u16 v;
        if (idx < 8192) {
            int j = idx & 7, lane = (idx >> 3) & 63, t = (idx >> 9) & 3, w = idx >> 11;
            int k = 32 * w + (lane >> 4) * 8 + j, n = 16 * t + (lane & 15);
            v = gldb(ew1, l * 129 * 64 + k * 64 + n, bf);
        } else if (idx < 12288) {
            int i2 = idx - 8192;
            int j = i2 & 7, lane = (i2 >> 3) & 63, t = (i2 >> 9) & 3, w = i2 >> 11;
            int k = 32 * w + (lane >> 4) * 8 + j, n = 16 * t + (lane & 15);
            v = gldb(ew2, l * 4096 + k * 64 + n, bf);
        } else {
            int i2 = idx - 12288;
            int j = i2 & 7, lane = (i2 >> 3) & 63, t = (i2 >> 9) & 3, w = i2 >> 11;
            int k = 32 * w + (lane >> 4) * 8 + j, n = 16 * t + (lane & 15);
            v = gldb(cw1, l * 4096 + k * 64 + n, bf);
        }
        pkE[l * LSE + idx] = v;
    }
    // edge fp32 consts: 4 layers x 320 (b1|b2|cb1|c2|wrad)
    for (int g = gid; g < 4 * 320; g += stride) {
        int l = g / 320, r = g % 320, wch = r >> 6, i = r & 63;
        float v = (wch == 0) ? gldf(eb1, l * 64 + i, bf)
                : (wch == 1) ? gldf(eb2, l * 64 + i, bf)
                : (wch == 2) ? gldf(cb1, l * 64 + i, bf)
                : (wch == 3) ? gldf(cw2, l * 64 + i, bf)
                :              gldf(ew1, l * 129 * 64 + 128 * 64 + i, bf);
        ((float*)(pkE + l * LSE + 16384))[r] = v;
    }
    // node weights: 4 layers x 6144 u32 (bf16 k-pairs)
    for (int g = gid; g < 4 * 6144; g += stride) {
        int l = g / 6144, idx = g % 6144;
        u32 pv;
        if (idx < 4096) {
            int kp = idx >> 6, j = idx & 63;
            u32 lo = gldb(nw1, l * 8192 + (2 * kp) * 64 + j, bf);
            u32 hi = gldb(nw1, l * 8192 + (2 * kp + 1) * 64 + j, bf);
            pv = lo | (hi << 16);
        } else {
            int i2 = idx - 4096, kp = i2 >> 6, j = i2 & 63;
            u32 lo = gldb(nw2, l * 4096 + (2 * kp) * 64 + j, bf);
            u32 hi = gldb(nw2, l * 4096 + (2 * kp + 1) * 64 + j, bf);
            pv = lo | (hi << 16);
        }
        pkN[l * LSN + idx] = pv;
    }
    // node biases: 4 layers x 128 f32 (nb1|nb2)
    for (int g = gid; g < 4 * 128; g += stride) {
        int l = g >> 7, r = g & 127;
        float v = (r < 64) ? gldf(nb1, l * 64 + r, bf) : gldf(nb2, l * 64 + (r - 64), bf);
        ((float*)(pkN + l * LSN + 6144))[r] = v;
    }
}

// ---- CSR build ----
__global__ void k_deg(const int* __restrict__ rowi, int* __restrict__ deg) {
    int e = blockIdx.x * 256 + threadIdx.x;
    if (e < EE) atomicAdd(&deg[rowi[e]], 1);
}

__global__ __launch_bounds__(1024) void k_scan(const int* deg, int* offs, int* cursor) {
    __shared__ int part[1024];
    const int tid = threadIdx.x;
    const int CH = (NN + 1023) / 1024;         // 20
    const int b0 = tid * CH;
    int s = 0;
    for (int i = 0; i < CH; i++) { int idx = b0 + i; if (idx < NN) s += deg[idx]; }
    part[tid] = s;
    __syncthreads();
    for (int d = 1; d < 1024; d <<= 1) {
        int v = (tid >= d) ? part[tid - d] : 0;
        __syncthreads();
        part[tid] += v;
        __syncthreads();
    }
    int run = (tid > 0) ? part[tid - 1] : 0;
    for (int i = 0; i < CH; i++) {
        int idx = b0 + i;
        if (idx < NN) {
            int dv = deg[idx];                  // read BEFORE overwrite (aliased)
            offs[idx] = run;
            cursor[idx] = run;
            run += dv;
        }
    }
    if (tid == 1023) offs[NN] = run;
}

// store the SENDER index directly (kills one dependent-load level)
__global__ void k_scatter(const int* __restrict__ rowi, const int* __restrict__ coli,
                          int* __restrict__ cursor, int* __restrict__ slist) {
    int e = blockIdx.x * 256 + threadIdx.x;
    if (e < EE) {
        int r = rowi[e];
        int pos = atomicAdd(&cursor[r], 1);
        slist[pos] = coli[e];
    }
}

// ---- input embedding: fp32 h + bf16 shadow ----
__global__ __launch_bounds__(256) void k_embed(
    const void* __restrict__ h_in, const void* __restrict__ x_in,
    const void* __restrict__ w, const void* __restrict__ bias,
    const int* __restrict__ flag,
    float* __restrict__ hws, float* __restrict__ xws, u16* __restrict__ hb)
{
    const int bf = *flag;
    const int lane = threadIdx.x & 63;
    const int wv   = threadIdx.x >> 6;
    const int i    = blockIdx.x * 4 + wv;
    float acc = gldf(bias, lane, bf);
    #pragma unroll
    for (int k = 0; k < 16; k++)
        acc = fmaf(gldf(h_in, i * 16 + k, bf), gldf(w, k * 64 + lane, bf), acc);
    hws[i * 64 + lane] = acc;
    hb[i * 64 + lane] = f2bf_rne(acc);
    if (lane < 3) xws[i * 3 + lane] = gldf(x_in, i * 3 + lane, bf);
}

// ---- edge model: MFMA, one wave per node, 16 edges per tile ----
// A-frag (16x16x32 bf16): A[m=lane&15][k=(lane>>4)*8+j]
// B-frag:                 B[k=(lane>>4)*8+j][n=lane&15]
// C/D:                    D[row=(lane>>4)*4+reg][col=lane&15]
// Single shared allocation; explicit offsets (u16 units):
//   [0      .. 8191 ]  stage-1 B frags (16 KB)
//   [8192   .. 16383]  stage-2|3 B frags (16 KB)
//   [16384  .. 21247]  4 wave M-tiles of 16*76 (pad 76 avoids 8-term bank cycle)
//   [21248  .. 21375]  sPhi: 4 waves * 16 f32 (as 2 u16 each)
#define OFF_B23  8192
#define OFF_M    16384
#define MPAD     76
#define OFF_PHI  (OFF_M + 4 * 16 * MPAD)
__global__ __launch_bounds__(256, 3) void k_edge(
    const u16* __restrict__ hb, const float* __restrict__ xws,
    const int* __restrict__ offs, const int* __restrict__ slist,
    const u16* __restrict__ pE,
    float* __restrict__ agg, float* __restrict__ xacc)
{
    __shared__ __align__(16) u16 sW[OFF_PHI + 4 * 16 * 2];

    const int tid = threadIdx.x, lane = tid & 63, wv = tid >> 6;
    const int l15 = lane & 15, quad = lane >> 4;

    // all weights: coalesced 16B copies from prepack into the single region
    for (int idx = tid; idx < 2048; idx += 256)
        ((s16x8*)sW)[idx] = ((const s16x8*)pE)[idx];
    const float* pb = (const float*)(pE + 16384);
    float b1v[4], b2v[4], cb1v[4], c2v[4], wrv[4];
    #pragma unroll
    for (int t = 0; t < 4; t++) {
        b1v[t]  = pb[       16 * t + l15];
        b2v[t]  = pb[ 64 +  16 * t + l15];
        cb1v[t] = pb[128 +  16 * t + l15];
        c2v[t]  = pb[192 +  16 * t + l15];
        wrv[t]  = pb[256 +  16 * t + l15];
    }
    __syncthreads();

    const int gw = blockIdx.x * 4 + wv, totW = gridDim.x * 4;
    u16* mrow = &sW[OFF_M + wv * 16 * MPAD];
    float* phiw = (float*)&sW[OFF_PHI + wv * 32];

    for (int n = gw; n < NN; n += totW) {
        const int o0 = offs[n], deg = offs[n + 1] - o0;
        if (deg == 0) continue;

        // node-uniform h_row A-frags straight from bf16 shadow table
        const s16x8 Ar0 = *(const s16x8*)&hb[n * 64 + quad * 8];
        const s16x8 Ar1 = *(const s16x8*)&hb[n * 64 + 32 + quad * 8];
        const float xrv = (quad < 3) ? xws[n * 3 + quad] : 0.0f;
        float aggA[4] = {0.f, 0.f, 0.f, 0.f};
        float xaccA = 0.0f;

        for (int eb = 0; eb < deg; eb += 16) {
            const int nb = min(16, deg - eb);
            const int ee = (l15 < nb) ? l15 : 0;
            const int ce = slist[o0 + eb + ee];         // edge-slot l15's sender
            float dx = 0.0f;
            if (quad < 3 && l15 < nb) dx = xrv - xws[ce * 3 + quad];
            float r2 = dx * dx;
            r2 += __shfl_xor(r2, 16, 64);
            r2 += __shfl_xor(r2, 32, 64);               // r2[edge l15], all lanes

            // ---- stage 1: e_in @ W1 ----
            f32x4 C[4] = {{0,0,0,0},{0,0,0,0},{0,0,0,0},{0,0,0,0}};
            #pragma unroll
            for (int t = 0; t < 4; t++) {
                const s16x8 Bf0 = *(const s16x8*)&sW[((0 * 4 + t) * 64 + lane) * 8];
                C[t] = __builtin_amdgcn_mfma_f32_16x16x32_bf16(Ar0, Bf0, C[t], 0, 0, 0);
                const s16x8 Bf1 = *(const s16x8*)&sW[((1 * 4 + t) * 64 + lane) * 8];
                C[t] = __builtin_amdgcn_mfma_f32_16x16x32_bf16(Ar1, Bf1, C[t], 0, 0, 0);
            }
            {
                const s16x8 Ac0 = *(const s16x8*)&hb[ce * 64 + quad * 8];
                const s16x8 Ac1 = *(const s16x8*)&hb[ce * 64 + 32 + quad * 8];
                #pragma unroll
                for (int t = 0; t < 4; t++) {
                    const s16x8 Bf2 = *(const s16x8*)&sW[((2 * 4 + t) * 64 + lane) * 8];
                    C[t] = __builtin_amdgcn_mfma_f32_16x16x32_bf16(Ac0, Bf2, C[t], 0, 0, 0);
                    const s16x8 Bf3 = *(const s16x8*)&sW[((3 * 4 + t) * 64 + lane) * 8];
                    C[t] = __builtin_amdgcn_mfma_f32_16x16x32_bf16(Ac1, Bf3, C[t], 0, 0, 0);
                }
            }
            // radial rank-1 + bias + silu; write to transform tile
            float r2r[4];
            #pragma unroll
            for (int r = 0; r < 4; r++) r2r[r] = __shfl(r2, quad * 4 + r, 64);
            #pragma unroll
            for (int t = 0; t < 4; t++)
                #pragma unroll
                for (int r = 0; r < 4; r++) {
                    float v = silu_f(C[t][r] + b1v[t] + r2r[r] * wrv[t]);
                    mrow[(quad * 4 + r) * MPAD + 16 * t + l15] = f2bf_rne(v);
                }

            // ---- stage 2: m = silu(a @ W2 + b2) ----
            f32x4 D[4] = {{0,0,0,0},{0,0,0,0},{0,0,0,0},{0,0,0,0}};
            #pragma unroll
            for (int w = 0; w < 2; w++) {
                const s16x8 Am = *(const s16x8*)(mrow + l15 * MPAD + 32 * w + quad * 8);
                #pragma unroll
                for (int t = 0; t < 4; t++) {
                    const s16x8 Bf = *(const s16x8*)&sW[OFF_B23 + ((w * 4 + t) * 64 + lane) * 8];
                    D[t] = __builtin_amdgcn_mfma_f32_16x16x32_bf16(Am, Bf, D[t], 0, 0, 0);
                }
            }
            #pragma unroll
            for (int t = 0; t < 4; t++)
                #pragma unroll
                for (int r = 0; r < 4; r++) {
                    float v = silu_f(D[t][r] + b2v[t]);
                    if (quad * 4 + r < nb) aggA[t] += v;     // fp32 agg, pre-rounding
                    mrow[(quad * 4 + r) * MPAD + 16 * t + l15] = f2bf_rne(v);
                }

            // ---- stage 3: p = silu(m @ C1 + cb1); phi = p . c2 ----
            f32x4 P[4] = {{0,0,0,0},{0,0,0,0},{0,0,0,0},{0,0,0,0}};
            #pragma unroll
            for (int w = 0; w < 2; w++) {
                const s16x8 Am = *(const s16x8*)(mrow + l15 * MPAD + 32 * w + quad * 8);
                #pragma unroll
                for (int t = 0; t < 4; t++) {
                    const s16x8 Bf = *(const s16x8*)&sW[OFF_B23 + (((2 + w) * 4 + t) * 64 + lane) * 8];
                    P[t] = __builtin_amdgcn_mfma_f32_16x16x32_bf16(Am, Bf, P[t], 0, 0, 0);
                }
            }
            float ph[4];
            #pragma unroll
            for (int r = 0; r < 4; r++) {
                float s = 0.f;
                #pragma unroll
                for (int t = 0; t < 4; t++) s = fmaf(silu_f(P[t][r] + cb1v[t]), c2v[t], s);
                s += __shfl_xor(s, 1, 64);
                s += __shfl_xor(s, 2, 64);
                s += __shfl_xor(s, 4, 64);
                s += __shfl_xor(s, 8, 64);
                ph[r] = s;                      // phi[row=quad*4+r]
            }
            if (l15 == 0) {
                #pragma unroll
                for (int r = 0; r < 4; r++) phiw[quad * 4 + r] = ph[r];
            }
            float phv = phiw[l15];              // per-wave in-order DS
            if (quad < 3 && l15 < nb) xaccA = fmaf(dx, phv, xaccA);
        }

        // ---- node epilogue: plain coalesced stores ----
        #pragma unroll
        for (int t = 0; t < 4; t++) {
            aggA[t] += __shfl_xor(aggA[t], 16, 64);
            aggA[t] += __shfl_xor(aggA[t], 32, 64);
        }
        float av = (quad == 0) ? aggA[0] : (quad == 1) ? aggA[1]
                 : (quad == 2) ? aggA[2] : aggA[3];
        agg[n * 64 + quad * 16 + l15] = av;

        xaccA += __shfl_xor(xaccA, 1, 64);
        xaccA += __shfl_xor(xaccA, 2, 64);
        xaccA += __shfl_xor(xaccA, 4, 64);
        xaccA += __shfl_xor(xaccA, 8, 64);
        if (l15 == 0 && quad < 3) xacc[n * 3 + quad] = xaccA / (float)deg;
    }
}

// ---- coord update: x += xacc (already mean-scaled; 0 for deg==0 nodes) ----
__global__ void k_coord(float* __restrict__ xws, const float* __restrict__ xacc) {
    int t = blockIdx.x * 256 + threadIdx.x;
    if (t < NN * 3) xws[t] += xacc[t];
}

// ---- node model: h += MLP([h, agg]); refresh bf16 shadow ----
__global__ __launch_bounds__(256) void k_node(
    float* __restrict__ hws, u16* __restrict__ hb, const float* __restrict__ agg,
    const u32* __restrict__ pN)
{
    __shared__ __align__(16) u32 sW1p[64 * 64];
    __shared__ __align__(16) u32 sW2p[32 * 64];
    __shared__ float sB1f[64], sB2f[64];
    __shared__ __align__(16) float sNin[4][8][132];

    const int tid = threadIdx.x, lane = tid & 63, wv = tid >> 6;
    for (int idx = tid; idx < 1024; idx += 256)
        ((f32x4*)sW1p)[idx] = ((const f32x4*)pN)[idx];
    for (int idx = tid; idx < 512; idx += 256)
        ((f32x4*)sW2p)[idx] = ((const f32x4*)(pN + 4096))[idx];
    const float* pb = (const float*)(pN + 6144);
    if (tid < 64) { sB1f[tid] = pb[tid]; sB2f[tid] = pb[64 + tid]; }
    __syncthreads();

    const int i0 = (blockIdx.x * 4 + wv) * 8;
    float hold[8];
    #pragma unroll
    for (int b = 0; b < 8; b++) {
        int i = i0 + b;
        float hv = hws[i * 64 + lane];
        hold[b] = hv;
        sNin[wv][b][lane]      = hv;
        sNin[wv][b][64 + lane] = agg[i * 64 + lane];
    }

    float acc[8];
    #pragma unroll
    for (int b = 0; b < 8; b++) acc[b] = sB1f[lane];
    #pragma unroll
    for (int kk = 0; kk < 32; kk++) {
        u32 w01 = sW1p[(kk * 2) * 64 + lane];
        u32 w23 = sW1p[(kk * 2 + 1) * 64 + lane];
        float w0 = __uint_as_float(w01 << 16), w1 = __uint_as_float(w01 & 0xffff0000u);
        float w2 = __uint_as_float(w23 << 16), w3 = __uint_as_float(w23 & 0xffff0000u);
        #pragma unroll
        for (int b = 0; b < 8; b++) {
            const float4 e4 = *reinterpret_cast<const float4*>(&sNin[wv][b][kk * 4]);
            acc[b] = fmaf(e4.x, w0, fmaf(e4.y, w1, fmaf(e4.z, w2, fmaf(e4.w, w3, acc[b]))));
        }
    }
    #pragma unroll
    for (int b = 0; b < 8; b++) acc[b] = silu_f(acc[b]);
    #pragma unroll
    for (int b = 0; b < 8; b++) sNin[wv][b][lane] = acc[b];

    float out[8];
    #pragma unroll
    for (int b = 0; b < 8; b++) out[b] = sB2f[lane];
    #pragma unroll
    for (int kk = 0; kk < 16; kk++) {
        u32 w01 = sW2p[(kk * 2) * 64 + lane];
        u32 w23 = sW2p[(kk * 2 + 1) * 64 + lane];
        float w0 = __uint_as_float(w01 << 16), w1 = __uint_as_float(w01 & 0xffff0000u);
        float w2 = __uint_as_float(w23 << 16), w3 = __uint_as_float(w23 & 0xffff0000u);
        #pragma unroll
        for (int b = 0; b < 8; b++) {
            const float4 e4 = *reinterpret_cast<const float4*>(&sNin[wv][b][kk * 4]);
            out[b] = fmaf(e4.x, w0, fmaf(e4.y, w1, fmaf(e4.z, w2, fmaf(e4.w, w3, out[b]))));
        }
    }
    #pragma unroll
    for (int b = 0; b < 8; b++) {
        float hv = hold[b] + out[b];
        hws[(i0 + b) * 64 + lane] = hv;
        hb[(i0 + b) * 64 + lane] = f2bf_rne(hv);
    }
}

// ---- output embedding + dtype-matched store ----
__global__ __launch_bounds__(256) void k_out(
    const float* __restrict__ hws, const float* __restrict__ xws,
    const void* __restrict__ wo, const void* __restrict__ bo,
    const int* __restrict__ flag, void* __restrict__ out)
{
    __shared__ u32 sWp[32 * 64];
    __shared__ float sBf[64];
    __shared__ __align__(16) float sH[4][8][68];
    const int tid = threadIdx.x, lane = tid & 63, wv = tid >> 6;
    const int bf = *flag;
    for (int idx = tid; idx < 32 * 64; idx += 256) {
        int kp = idx >> 6, j = idx & 63;
        u32 lo = gldb(wo, (kp * 2) * 64 + j, bf);
        u32 hi = gldb(wo, (kp * 2 + 1) * 64 + j, bf);
        sWp[idx] = lo | (hi << 16);
    }
    if (tid < 64) sBf[tid] = gldf(bo, tid, bf);
    __syncthreads();

    const int i0 = (blockIdx.x * 4 + wv) * 8;
    #pragma unroll
    for (int b = 0; b < 8; b++) sH[wv][b][lane] = hws[(i0 + b) * 64 + lane];

    float acc[8];
    #pragma unroll
    for (int b = 0; b < 8; b++) acc[b] = sBf[lane];
    #pragma unroll
    for (int kk = 0; kk < 16; kk++) {
        u32 w01 = sWp[(kk * 2) * 64 + lane];
        u32 w23 = sWp[(kk * 2 + 1) * 64 + lane];
        float w0 = __uint_as_float(w01 << 16), w1 = __uint_as_float(w01 & 0xffff0000u);
        float w2 = __uint_as_float(w23 << 16), w3 = __uint_as_float(w23 & 0xffff0000u);
        #pragma unroll
        for (int b = 0; b < 8; b++) {
            const float4 e4 = *reinterpret_cast<const float4*>(&sH[wv][b][kk * 4]);
            acc[b] = fmaf(e4.x, w0, fmaf(e4.y, w1, fmaf(e4.z, w2, fmaf(e4.w, w3, acc[b]))));
        }
    }
    u16*   oh16 = (u16*)out;
    float* ohf  = (float*)out;
    u16*   ox16 = oh16 + (size_t)NN * 64;
    float* oxf  = ohf  + (size_t)NN * 64;
    #pragma unroll
    for (int b = 0; b < 8; b++) {
        int i = i0 + b;
        if (bf) {
            oh16[i * 64 + lane] = f2bf_rne(acc[b]);
            if (lane < 3) ox16[i * 3 + lane] = f2bf_rne(xws[i * 3 + lane]);
        } else {
            ohf[i * 64 + lane] = acc[b];
            if (lane < 3) oxf[i * 3 + lane] = xws[i * 3 + lane];
        }
    }
}

extern "C" void kernel_launch(void* const* d_in, const int* in_sizes, int n_in,
                              void* d_out, int out_size, void* d_ws, size_t ws_size,
                              hipStream_t stream)
{
    const size_t WS_REQ = (size_t)NN * 134 * sizeof(float) + 64;
    if (ws_size < WS_REQ) {
        float sval = 1000.0f + (float)(ws_size >> 20);
        k_sentinel<<<(out_size + 255) / 256, 256, 0, stream>>>(
            (u16*)d_out, out_size, sval);
        return;
    }

    const void* h_in = d_in[0];
    const void* x_in = d_in[1];
    const int*  eidx = (const int*)d_in[2];
    const int* rowi = eidx;
    const int* coli = eidx + EE;

    float* ws   = (float*)d_ws;
    float* hws  = ws;                          // N*64
    float* xws  = hws + NN * 64;               // N*3
    float* agg  = xws + NN * 3;                // N*64
    float* xacc = agg + NN * 64;               // N*3
    int*   flag = (int*)(xacc + NN * 3);       // 1
    int*   cursor = (int*)xacc;                // aliased: dead before xacc use

    // d_out scratch until k_out overwrites it (fp32 out = 5.36 MB)
    u16* hb    = (u16*)d_out;                  // N*64 bf16  (2.56 MB, 16B-aligned)
    int* offs  = (int*)(hb + (size_t)NN * 64); // N+4 (padded -> pkE 16B-aligned)
    int* slist = offs + (NN + 4);              // E
    u16* pkE   = (u16*)(slist + EE);           // 4*LSE u16  (136 KB)
    u32* pkN   = (u32*)(pkE + 4 * LSE);        // 4*LSN u32  (100 KB)

    hipMemsetAsync(cursor, 0, (size_t)NN * sizeof(int), stream);

    k_detect<<<1, 128, 0, stream>>>((const u16*)h_in, flag);
    k_pack<<<64, 256, 0, stream>>>(d_in[5], d_in[6], d_in[7], d_in[8], d_in[9],
                                   d_in[10], d_in[11], d_in[12], d_in[13],
                                   d_in[14], d_in[15], flag, pkE, pkN);
    k_deg<<<(EE + 255) / 256, 256, 0, stream>>>(rowi, cursor);
    k_scan<<<1, 1024, 0, stream>>>(cursor, offs, cursor);
    k_scatter<<<(EE + 255) / 256, 256, 0, stream>>>(rowi, coli, cursor, slist);

    // zero agg|xacc AFTER CSR build (cursor aliased xacc)
    hipMemsetAsync(agg, 0, (size_t)NN * 67 * sizeof(float), stream);

    k_embed<<<NN / 4, 256, 0, stream>>>(h_in, x_in, d_in[3], d_in[4], flag, hws, xws, hb);

    for (int l = 0; l < 4; l++) {
        k_edge<<<1536, 256, 0, stream>>>(hb, xws, offs, slist,
                                         pkE + l * LSE, agg, xacc);
        k_coord<<<(NN * 3 + 255) / 256, 256, 0, stream>>>(xws, xacc);
        k_node<<<NN / 32, 256, 0, stream>>>(hws, hb, agg, pkN + (size_t)l * LSN);
    }
    k_out<<<NN / 32, 256, 0, stream>>>(hws, xws, d_in[16], d_in[17], flag, d_out);
}

// Round 10
// 576.700 us; speedup vs baseline: 2.1100x; 1.0291x over previous
//
#include <hip/hip_runtime.h>
#include <hip/hip_bf16.h>

// EGNN forward, MI355X. fp32 tensors (runtime-detected, bf16 path kept).
// CSR edge processing, bf16 MFMA edge MLPs, L2-resident bf16 h shadow table,
// per-call weight PREPACK. R10: hoisted per-node stage-1 base MFMA, grid=768
// (all-resident), k_coord fused into k_node, detect+deg fused into k_pack.
// ws (floats): h[N*64] | x[N*3] | agg[N*64] | xacc[N*3] | flag
// d_out scratch until k_out:
//   hb[N*64 bf16] | offs[N+4] | slist[E] | pkE[4*17024 u16] | pkN[4*6272 u32] | cursor[N]

#define NN 20000
#define EE 320000
#define LSE 17024      // per-layer u16 stride, edge pack: 8192 W1 | 4096 W2 | 4096 C1 | 320 f32
#define LSN 6272       // per-layer u32 stride, node pack: 4096 W1 | 2048 W2 | 128 f32

typedef unsigned short u16;
typedef unsigned int   u32;
typedef __attribute__((ext_vector_type(8))) short s16x8;   // 8 bf16 (A/B frag)
typedef __attribute__((ext_vector_type(4))) float f32x4;   // C/D frag

__device__ __forceinline__ float bf2f(u16 u) { return __uint_as_float(((u32)u) << 16); }
__device__ __forceinline__ float silu_f(float x) { return x / (1.0f + __expf(-x)); }

__device__ __forceinline__ u16 f2bf_rne(float f) {
    u32 u = __float_as_uint(f);
    return (u16)((u + 0x7FFFu + ((u >> 16) & 1u)) >> 16);
}
__device__ __forceinline__ float gldf(const void* p, int i, int bf) {
    return bf ? bf2f(((const u16*)p)[i]) : ((const float*)p)[i];
}
__device__ __forceinline__ u16 gldb(const void* p, int i, int bf) {
    return bf ? ((const u16*)p)[i] : f2bf_rne(((const float*)p)[i]);
}

__global__ void k_sentinel(u16* __restrict__ out, int n, float v) {
    int t = blockIdx.x * 256 + threadIdx.x;
    if (t < n) out[t] = f2bf_rne(v);
}

// ---- fused: weight prepack (blocks 0..63, each detects dtype locally;
//      block 0 publishes flag) + degree count (blocks 64..) ----
__global__ __launch_bounds__(256) void k_pack(
    const void* __restrict__ ew1, const void* __restrict__ eb1,
    const void* __restrict__ ew2, const void* __restrict__ eb2,
    const void* __restrict__ cw1, const void* __restrict__ cb1,
    const void* __restrict__ cw2,
    const void* __restrict__ nw1, const void* __restrict__ nb1,
    const void* __restrict__ nw2, const void* __restrict__ nb2,
    const u16* __restrict__ h_raw, const int* __restrict__ rowi,
    int* __restrict__ flag, int* __restrict__ deg,
    u16* __restrict__ pkE, u32* __restrict__ pkN)
{
    if (blockIdx.x >= 64) {                    // degree-count blocks
        int e = (blockIdx.x - 64) * 256 + threadIdx.x;
        if (e < EE) atomicAdd(&deg[rowi[e]], 1);
        return;
    }
    // local dtype detection (cheap; every pack block decides independently)
    __shared__ int cnt_s;
    if (threadIdx.x == 0) cnt_s = 0;
    __syncthreads();
    if (threadIdx.x < 128) {
        float v = fabsf(bf2f(h_raw[threadIdx.x]));
        if (v >= 0.015625f && v <= 16.0f) atomicAdd(&cnt_s, 1);
    }
    __syncthreads();
    const int bf = (cnt_s >= 96) ? 1 : 0;
    if (blockIdx.x == 0 && threadIdx.x == 0) *flag = bf;

    const int gid = blockIdx.x * 256 + threadIdx.x;
    const int stride = 64 * 256;

    // edge weights: 4 layers x 16384 u16
    for (int g = gid; g < 4 * 16384; g += stride) {
        int l = g >> 14, idx = g & 16383;
        u16 v;
        if (idx < 8192) {
            int j = idx & 7, lane = (idx >> 3) & 63, t = (idx >> 9) & 3, w = idx >> 11;
            int k = 32 * w + (lane >> 4) * 8 + j, n = 16 * t + (lane & 15);
            v = gldb(ew1, l * 129 * 64 + k * 64 + n, bf);
        } else if (idx < 12288) {
            int i2 = idx - 8192;
            int j = i2 & 7, lane = (i2 >> 3) & 63, t = (i2 >> 9) & 3, w = i2 >> 11;
            int k = 32 * w + (lane >> 4) * 8 + j, n = 16 * t + (lane & 15);
            v = gldb(ew2, l * 4096 + k * 64 + n, bf);
        } else {
            int i2 = idx - 12288;
            int j = i2 & 7, lane = (i2 >> 3) & 63, t = (i2 >> 9) & 3, w = i2 >> 11;
            int k = 32 * w + (lane >> 4) * 8 + j, n = 16 * t + (lane & 15);
            v = gldb(cw1, l * 4096 + k * 64 + n, bf);
        }
        pkE[l * LSE + idx] = v;
    }
    // edge fp32 consts: 4 layers x 320 (b1|b2|cb1|c2|wrad)
    for (int g = gid; g < 4 * 320; g += stride) {
        int l = g / 320, r = g % 320, wch = r >> 6, i = r & 63;
        float v = (wch == 0) ? gldf(eb1, l * 64 + i, bf)
                : (wch == 1) ? gldf(eb2, l * 64 + i, bf)
                : (wch == 2) ? gldf(cb1, l * 64 + i, bf)
                : (wch == 3) ? gldf(cw2, l * 64 + i, bf)
                :              gldf(ew1, l * 129 * 64 + 128 * 64 + i, bf);
        ((float*)(pkE + l * LSE + 16384))[r] = v;
    }
    // node weights: 4 layers x 6144 u32 (bf16 k-pairs)
    for (int g = gid; g < 4 * 6144; g += stride) {
        int l = g / 6144, idx = g % 6144;
        u32 pv;
        if (idx < 4096) {
            int kp = idx >> 6, j = idx & 63;
            u32 lo = gldb(nw1, l * 8192 + (2 * kp) * 64 + j, bf);
            u32 hi = gldb(nw1, l * 8192 + (2 * kp + 1) * 64 + j, bf);
            pv = lo | (hi << 16);
        } else {
            int i2 = idx - 4096, kp = i2 >> 6, j = i2 & 63;
            u32 lo = gldb(nw2, l * 4096 + (2 * kp) * 64 + j, bf);
            u32 hi = gldb(nw2, l * 4096 + (2 * kp + 1) * 64 + j, bf);
            pv = lo | (hi << 16);
        }
        pkN[l * LSN + idx] = pv;
    }
    // node biases: 4 layers x 128 f32 (nb1|nb2)
    for (int g = gid; g < 4 * 128; g += stride) {
        int l = g >> 7, r = g & 127;
        float v = (r < 64) ? gldf(nb1, l * 64 + r, bf) : gldf(nb2, l * 64 + (r - 64), bf);
        ((float*)(pkN + l * LSN + 6144))[r] = v;
    }
}

// ---- CSR scan + scatter ----
__global__ __launch_bounds__(1024) void k_scan(const int* deg, int* offs, int* cursor) {
    __shared__ int part[1024];
    const int tid = threadIdx.x;
    const int CH = (NN + 1023) / 1024;         // 20
    const int b0 = tid * CH;
    int s = 0;
    for (int i = 0; i < CH; i++) { int idx = b0 + i; if (idx < NN) s += deg[idx]; }
    part[tid] = s;
    __syncthreads();
    for (int d = 1; d < 1024; d <<= 1) {
        int v = (tid >= d) ? part[tid - d] : 0;
        __syncthreads();
        part[tid] += v;
        __syncthreads();
    }
    int run = (tid > 0) ? part[tid - 1] : 0;
    for (int i = 0; i < CH; i++) {
        int idx = b0 + i;
        if (idx < NN) {
            int dv = deg[idx];                  // read BEFORE overwrite (aliased)
            offs[idx] = run;
            cursor[idx] = run;
            run += dv;
        }
    }
    if (tid == 1023) offs[NN] = run;
}

__global__ void k_scatter(const int* __restrict__ rowi, const int* __restrict__ coli,
                          int* __restrict__ cursor, int* __restrict__ slist) {
    int e = blockIdx.x * 256 + threadIdx.x;
    if (e < EE) {
        int r = rowi[e];
        int pos = atomicAdd(&cursor[r], 1);
        slist[pos] = coli[e];
    }
}

// ---- input embedding: fp32 h + bf16 shadow ----
__global__ __launch_bounds__(256) void k_embed(
    const void* __restrict__ h_in, const void* __restrict__ x_in,
    const void* __restrict__ w, const void* __restrict__ bias,
    const int* __restrict__ flag,
    float* __restrict__ hws, float* __restrict__ xws, u16* __restrict__ hb)
{
    const int bf = *flag;
    const int lane = threadIdx.x & 63;
    const int wv   = threadIdx.x >> 6;
    const int i    = blockIdx.x * 4 + wv;
    float acc = gldf(bias, lane, bf);
    #pragma unroll
    for (int k = 0; k < 16; k++)
        acc = fmaf(gldf(h_in, i * 16 + k, bf), gldf(w, k * 64 + lane, bf), acc);
    hws[i * 64 + lane] = acc;
    hb[i * 64 + lane] = f2bf_rne(acc);
    if (lane < 3) xws[i * 3 + lane] = gldf(x_in, i * 3 + lane, bf);
}

// ---- edge model: MFMA, one wave per node, 16 edges per tile ----
// A-frag (16x16x32 bf16): A[m=lane&15][k=(lane>>4)*8+j]
// B-frag:                 B[k=(lane>>4)*8+j][n=lane&15]
// C/D:                    D[row=(lane>>4)*4+reg][col=lane&15]
// Single shared allocation; explicit offsets (u16 units).
#define OFF_B23  8192
#define OFF_M    16384
#define MPAD     76
#define OFF_PHI  (OFF_M + 4 * 16 * MPAD)
__global__ __launch_bounds__(256, 3) void k_edge(
    const u16* __restrict__ hb, const float* __restrict__ xws,
    const int* __restrict__ offs, const int* __restrict__ slist,
    const u16* __restrict__ pE,
    float* __restrict__ agg, float* __restrict__ xacc)
{
    __shared__ __align__(16) u16 sW[OFF_PHI + 4 * 16 * 2];

    const int tid = threadIdx.x, lane = tid & 63, wv = tid >> 6;
    const int l15 = lane & 15, quad = lane >> 4;

    for (int idx = tid; idx < 2048; idx += 256)
        ((s16x8*)sW)[idx] = ((const s16x8*)pE)[idx];
    const float* pb = (const float*)(pE + 16384);
    float b1v[4], b2v[4], cb1v[4], c2v[4], wrv[4];
    #pragma unroll
    for (int t = 0; t < 4; t++) {
        b1v[t]  = pb[       16 * t + l15];
        b2v[t]  = pb[ 64 +  16 * t + l15];
        cb1v[t] = pb[128 +  16 * t + l15];
        c2v[t]  = pb[192 +  16 * t + l15];
        wrv[t]  = pb[256 +  16 * t + l15];
    }
    __syncthreads();

    const int gw = blockIdx.x * 4 + wv, totW = gridDim.x * 4;
    u16* mrow = &sW[OFF_M + wv * 16 * MPAD];
    float* phiw = (float*)&sW[OFF_PHI + wv * 32];

    for (int n = gw; n < NN; n += totW) {
        const int o0 = offs[n], deg = offs[n + 1] - o0;
        if (deg == 0) continue;

        // hoisted per-node base: Cbase[t] = h_row @ W1[rows 0..63]
        const s16x8 Ar0 = *(const s16x8*)&hb[n * 64 + quad * 8];
        const s16x8 Ar1 = *(const s16x8*)&hb[n * 64 + 32 + quad * 8];
        f32x4 Cb[4] = {{0,0,0,0},{0,0,0,0},{0,0,0,0},{0,0,0,0}};
        #pragma unroll
        for (int t = 0; t < 4; t++) {
            const s16x8 Bf0 = *(const s16x8*)&sW[((0 * 4 + t) * 64 + lane) * 8];
            Cb[t] = __builtin_amdgcn_mfma_f32_16x16x32_bf16(Ar0, Bf0, Cb[t], 0, 0, 0);
            const s16x8 Bf1 = *(const s16x8*)&sW[((1 * 4 + t) * 64 + lane) * 8];
            Cb[t] = __builtin_amdgcn_mfma_f32_16x16x32_bf16(Ar1, Bf1, Cb[t], 0, 0, 0);
        }
        const float xrv = (quad < 3) ? xws[n * 3 + quad] : 0.0f;
        float aggA[4] = {0.f, 0.f, 0.f, 0.f};
        float xaccA = 0.0f;

        for (int eb = 0; eb < deg; eb += 16) {
            const int nb = min(16, deg - eb);
            const int ee = (l15 < nb) ? l15 : 0;
            const int ce = slist[o0 + eb + ee];         // edge-slot l15's sender
            float dx = 0.0f;
            if (quad < 3 && l15 < nb) dx = xrv - xws[ce * 3 + quad];
            float r2 = dx * dx;
            r2 += __shfl_xor(r2, 16, 64);
            r2 += __shfl_xor(r2, 32, 64);               // r2[edge l15], all lanes

            // ---- stage 1: start from Cbase, add h_col @ W1[rows 64..127] ----
            f32x4 C[4] = {Cb[0], Cb[1], Cb[2], Cb[3]};
            {
                const s16x8 Ac0 = *(const s16x8*)&hb[ce * 64 + quad * 8];
                const s16x8 Ac1 = *(const s16x8*)&hb[ce * 64 + 32 + quad * 8];
                #pragma unroll
                for (int t = 0; t < 4; t++) {
                    const s16x8 Bf2 = *(const s16x8*)&sW[((2 * 4 + t) * 64 + lane) * 8];
                    C[t] = __builtin_amdgcn_mfma_f32_16x16x32_bf16(Ac0, Bf2, C[t], 0, 0, 0);
                    const s16x8 Bf3 = *(const s16x8*)&sW[((3 * 4 + t) * 64 + lane) * 8];
                    C[t] = __builtin_amdgcn_mfma_f32_16x16x32_bf16(Ac1, Bf3, C[t], 0, 0, 0);
                }
            }
            // radial rank-1 + bias + silu; write to transform tile
            float r2r[4];
            #pragma unroll
            for (int r = 0; r < 4; r++) r2r[r] = __shfl(r2, quad * 4 + r, 64);
            #pragma unroll
            for (int t = 0; t < 4; t++)
                #pragma unroll
                for (int r = 0; r < 4; r++) {
                    float v = silu_f(C[t][r] + b1v[t] + r2r[r] * wrv[t]);
                    mrow[(quad * 4 + r) * MPAD + 16 * t + l15] = f2bf_rne(v);
                }

            // ---- stage 2: m = silu(a @ W2 + b2) ----
            f32x4 D[4] = {{0,0,0,0},{0,0,0,0},{0,0,0,0},{0,0,0,0}};
            #pragma unroll
            for (int w = 0; w < 2; w++) {
                const s16x8 Am = *(const s16x8*)(mrow + l15 * MPAD + 32 * w + quad * 8);
                #pragma unroll
                for (int t = 0; t < 4; t++) {
                    const s16x8 Bf = *(const s16x8*)&sW[OFF_B23 + ((w * 4 + t) * 64 + lane) * 8];
                    D[t] = __builtin_amdgcn_mfma_f32_16x16x32_bf16(Am, Bf, D[t], 0, 0, 0);
                }
            }
            #pragma unroll
            for (int t = 0; t < 4; t++)
                #pragma unroll
                for (int r = 0; r < 4; r++) {
                    float v = silu_f(D[t][r] + b2v[t]);
                    if (quad * 4 + r < nb) aggA[t] += v;     // fp32 agg, pre-rounding
                    mrow[(quad * 4 + r) * MPAD + 16 * t + l15] = f2bf_rne(v);
                }

            // ---- stage 3: p = silu(m @ C1 + cb1); phi = p . c2 ----
            f32x4 P[4] = {{0,0,0,0},{0,0,0,0},{0,0,0,0},{0,0,0,0}};
            #pragma unroll
            for (int w = 0; w < 2; w++) {
                const s16x8 Am = *(const s16x8*)(mrow + l15 * MPAD + 32 * w + quad * 8);
                #pragma unroll
                for (int t = 0; t < 4; t++) {
                    const s16x8 Bf = *(const s16x8*)&sW[OFF_B23 + (((2 + w) * 4 + t) * 64 + lane) * 8];
                    P[t] = __builtin_amdgcn_mfma_f32_16x16x32_bf16(Am, Bf, P[t], 0, 0, 0);
                }
            }
            float ph[4];
            #pragma unroll
            for (int r = 0; r < 4; r++) {
                float s = 0.f;
                #pragma unroll
                for (int t = 0; t < 4; t++) s = fmaf(silu_f(P[t][r] + cb1v[t]), c2v[t], s);
                s += __shfl_xor(s, 1, 64);
                s += __shfl_xor(s, 2, 64);
                s += __shfl_xor(s, 4, 64);
                s += __shfl_xor(s, 8, 64);
                ph[r] = s;                      // phi[row=quad*4+r]
            }
            if (l15 == 0) {
                #pragma unroll
                for (int r = 0; r < 4; r++) phiw[quad * 4 + r] = ph[r];
            }
            float phv = phiw[l15];              // per-wave in-order DS
            if (quad < 3 && l15 < nb) xaccA = fmaf(dx, phv, xaccA);
        }

        // ---- node epilogue: plain coalesced stores ----
        #pragma unroll
        for (int t = 0; t < 4; t++) {
            aggA[t] += __shfl_xor(aggA[t], 16, 64);
            aggA[t] += __shfl_xor(aggA[t], 32, 64);
        }
        float av = (quad == 0) ? aggA[0] : (quad == 1) ? aggA[1]
                 : (quad == 2) ? aggA[2] : aggA[3];
        agg[n * 64 + quad * 16 + l15] = av;

        xaccA += __shfl_xor(xaccA, 1, 64);
        xaccA += __shfl_xor(xaccA, 2, 64);
        xaccA += __shfl_xor(xaccA, 4, 64);
        xaccA += __shfl_xor(xaccA, 8, 64);
        if (l15 == 0 && quad < 3) xacc[n * 3 + quad] = xaccA / (float)deg;
    }
}

// ---- node model (coord update fused): x += xacc; h += MLP([h, agg]) ----
__global__ __launch_bounds__(256) void k_node(
    float* __restrict__ hws, u16* __restrict__ hb, const float* __restrict__ agg,
    float* __restrict__ xws, const float* __restrict__ xacc,
    const u32* __restrict__ pN)
{
    __shared__ __align__(16) u32 sW1p[64 * 64];
    __shared__ __align__(16) u32 sW2p[32 * 64];
    __shared__ float sB1f[64], sB2f[64];
    __shared__ __align__(16) float sNin[4][8][132];

    const int tid = threadIdx.x, lane = tid & 63, wv = tid >> 6;
    for (int idx = tid; idx < 1024; idx += 256)
        ((f32x4*)sW1p)[idx] = ((const f32x4*)pN)[idx];
    for (int idx = tid; idx < 512; idx += 256)
        ((f32x4*)sW2p)[idx] = ((const f32x4*)(pN + 4096))[idx];
    const float* pb = (const float*)(pN + 6144);
    if (tid < 64) { sB1f[tid] = pb[tid]; sB2f[tid] = pb[64 + tid]; }

    // fused coord update: 32 nodes/block -> 96 floats, lanes of wave 0..1
    {
        int t = blockIdx.x * 96 + tid;          // covers 96 < 256 threads
        if (tid < 96) xws[t] += xacc[t];
    }
    __syncthreads();

    const int i0 = (blockIdx.x * 4 + wv) * 8;
    float hold[8];
    #pragma unroll
    for (int b = 0; b < 8; b++) {
        int i = i0 + b;
        float hv = hws[i * 64 + lane];
        hold[b] = hv;
        sNin[wv][b][lane]      = hv;
        sNin[wv][b][64 + lane] = agg[i * 64 + lane];
    }

    float acc[8];
    #pragma unroll
    for (int b = 0; b < 8; b++) acc[b] = sB1f[lane];
    #pragma unroll
    for (int kk = 0; kk < 32; kk++) {
        u32 w01 = sW1p[(kk * 2) * 64 + lane];
        u32 w23 = sW1p[(kk * 2 + 1) * 64 + lane];
        float w0 = __uint_as_float(w01 << 16), w1 = __uint_as_float(w01 & 0xffff0000u);
        float w2 = __uint_as_float(w23 << 16), w3 = __uint_as_float(w23 & 0xffff0000u);
        #pragma unroll
        for (int b = 0; b < 8; b++) {
            const float4 e4 = *reinterpret_cast<const float4*>(&sNin[wv][b][kk * 4]);
            acc[b] = fmaf(e4.x, w0, fmaf(e4.y, w1, fmaf(e4.z, w2, fmaf(e4.w, w3, acc[b]))));
        }
    }
    #pragma unroll
    for (int b = 0; b < 8; b++) acc[b] = silu_f(acc[b]);
    #pragma unroll
    for (int b = 0; b < 8; b++) sNin[wv][b][lane] = acc[b];

    float out[8];
    #pragma unroll
    for (int b = 0; b < 8; b++) out[b] = sB2f[lane];
    #pragma unroll
    for (int kk = 0; kk < 16; kk++) {
        u32 w01 = sW2p[(kk * 2) * 64 + lane];
        u32 w23 = sW2p[(kk * 2 + 1) * 64 + lane];
        float w0 = __uint_as_float(w01 << 16), w1 = __uint_as_float(w01 & 0xffff0000u);
        float w2 = __uint_as_float(w23 << 16), w3 = __uint_as_float(w23 & 0xffff0000u);
        #pragma unroll
        for (int b = 0; b < 8; b++) {
            const float4 e4 = *reinterpret_cast<const float4*>(&sNin[wv][b][kk * 4]);
            out[b] = fmaf(e4.x, w0, fmaf(e4.y, w1, fmaf(e4.z, w2, fmaf(e4.w, w3, out[b]))));
        }
    }
    #pragma unroll
    for (int b = 0; b < 8; b++) {
        float hv = hold[b] + out[b];
        hws[(i0 + b) * 64 + lane] = hv;
        hb[(i0 + b) * 64 + lane] = f2bf_rne(hv);
    }
}

// ---- output embedding + dtype-matched store ----
__global__ __launch_bounds__(256) void k_out(
    const float* __restrict__ hws, const float* __restrict__ xws,
    const void* __restrict__ wo, const void* __restrict__ bo,
    const int* __restrict__ flag, void* __restrict__ out)
{
    __shared__ u32 sWp[32 * 64];
    __shared__ float sBf[64];
    __shared__ __align__(16) float sH[4][8][68];
    const int tid = threadIdx.x, lane = tid & 63, wv = tid >> 6;
    const int bf = *flag;
    for (int idx = tid; idx < 32 * 64; idx += 256) {
        int kp = idx >> 6, j = idx & 63;
        u32 lo = gldb(wo, (kp * 2) * 64 + j, bf);
        u32 hi = gldb(wo, (kp * 2 + 1) * 64 + j, bf);
        sWp[idx] = lo | (hi << 16);
    }
    if (tid < 64) sBf[tid] = gldf(bo, tid, bf);
    __syncthreads();

    const int i0 = (blockIdx.x * 4 + wv) * 8;
    #pragma unroll
    for (int b = 0; b < 8; b++) sH[wv][b][lane] = hws[(i0 + b) * 64 + lane];

    float acc[8];
    #pragma unroll
    for (int b = 0; b < 8; b++) acc[b] = sBf[lane];
    #pragma unroll
    for (int kk = 0; kk < 16; kk++) {
        u32 w01 = sWp[(kk * 2) * 64 + lane];
        u32 w23 = sWp[(kk * 2 + 1) * 64 + lane];
        float w0 = __uint_as_float(w01 << 16), w1 = __uint_as_float(w01 & 0xffff0000u);
        float w2 = __uint_as_float(w23 << 16), w3 = __uint_as_float(w23 & 0xffff0000u);
        #pragma unroll
        for (int b = 0; b < 8; b++) {
            const float4 e4 = *reinterpret_cast<const float4*>(&sH[wv][b][kk * 4]);
            acc[b] = fmaf(e4.x, w0, fmaf(e4.y, w1, fmaf(e4.z, w2, fmaf(e4.w, w3, acc[b]))));
        }
    }
    u16*   oh16 = (u16*)out;
    float* ohf  = (float*)out;
    u16*   ox16 = oh16 + (size_t)NN * 64;
    float* oxf  = ohf  + (size_t)NN * 64;
    #pragma unroll
    for (int b = 0; b < 8; b++) {
        int i = i0 + b;
        if (bf) {
            oh16[i * 64 + lane] = f2bf_rne(acc[b]);
            if (lane < 3) ox16[i * 3 + lane] = f2bf_rne(xws[i * 3 + lane]);
        } else {
            ohf[i * 64 + lane] = acc[b];
            if (lane < 3) oxf[i * 3 + lane] = xws[i * 3 + lane];
        }
    }
}

extern "C" void kernel_launch(void* const* d_in, const int* in_sizes, int n_in,
                              void* d_out, int out_size, void* d_ws, size_t ws_size,
                              hipStream_t stream)
{
    const size_t WS_REQ = (size_t)NN * 134 * sizeof(float) + 64;
    if (ws_size < WS_REQ) {
        float sval = 1000.0f + (float)(ws_size >> 20);
        k_sentinel<<<(out_size + 255) / 256, 256, 0, stream>>>(
            (u16*)d_out, out_size, sval);
        return;
    }

    const void* h_in = d_in[0];
    const void* x_in = d_in[1];
    const int*  eidx = (const int*)d_in[2];
    const int* rowi = eidx;
    const int* coli = eidx + EE;

    float* ws   = (float*)d_ws;
    float* hws  = ws;                          // N*64
    float* xws  = hws + NN * 64;               // N*3
    float* agg  = xws + NN * 3;                // N*64
    float* xacc = agg + NN * 64;               // N*3
    int*   flag = (int*)(xacc + NN * 3);       // 1

    // d_out scratch until k_out overwrites it (fp32 out = 5.36 MB)
    u16* hb     = (u16*)d_out;                 // N*64 bf16  (2.56 MB)
    int* offs   = (int*)(hb + (size_t)NN * 64);// N+4
    int* slist  = offs + (NN + 4);             // E
    u16* pkE    = (u16*)(slist + EE);          // 4*LSE u16  (136 KB, 16B-aligned)
    u32* pkN    = (u32*)(pkE + 4 * LSE);       // 4*LSN u32  (100 KB)
    int* cursor = (int*)(pkN + 4 * LSN);       // N  (deg, then scatter cursor)

    hipMemsetAsync(cursor, 0, (size_t)NN * sizeof(int), stream);
    hipMemsetAsync(agg, 0, (size_t)NN * 67 * sizeof(float), stream);

    k_pack<<<64 + (EE + 255) / 256, 256, 0, stream>>>(
        d_in[5], d_in[6], d_in[7], d_in[8], d_in[9], d_in[10], d_in[11],
        d_in[12], d_in[13], d_in[14], d_in[15],
        (const u16*)h_in, rowi, flag, cursor, pkE, pkN);
    k_scan<<<1, 1024, 0, stream>>>(cursor, offs, cursor);
    k_scatter<<<(EE + 255) / 256, 256, 0, stream>>>(rowi, coli, cursor, slist);
    k_embed<<<NN / 4, 256, 0, stream>>>(h_in, x_in, d_in[3], d_in[4], flag, hws, xws, hb);

    for (int l = 0; l < 4; l++) {
        k_edge<<<768, 256, 0, stream>>>(hb, xws, offs, slist,
                                        pkE + l * LSE, agg, xacc);
        k_node<<<NN / 32, 256, 0, stream>>>(hws, hb, agg, xws, xacc,
                                            pkN + (size_t)l * LSN);
    }
    k_out<<<NN / 32, 256, 0, stream>>>(hws, xws, d_in[16], d_in[17], flag, d_out);
}